// Round 13
// baseline (6290.726 us; speedup 1.0000x reference)
//
#include <hip/hip_runtime.h>
#include <hip/hip_bf16.h>

#define DEV __device__ __forceinline__

typedef __attribute__((ext_vector_type(4))) float f32x4;
typedef __attribute__((ext_vector_type(8))) short short8;
typedef __attribute__((ext_vector_type(8))) _Float16 f16x8;
typedef __attribute__((ext_vector_type(4))) int i32x4;
typedef __attribute__((ext_vector_type(4))) unsigned short u16x4;

typedef __attribute__((address_space(3))) void lds_void;
typedef const __attribute__((address_space(1))) void g_void;
#define GLOAD16(g, l) __builtin_amdgcn_global_load_lds((g_void*)(g), (lds_void*)(l), 16, 0, 0)

DEV unsigned short f2h(float f){ union{_Float16 h; unsigned short u;} c; c.h = (_Float16)f; return c.u; }
DEV float h2f(unsigned short u){ union{unsigned short u; _Float16 h;} c; c.u = u; return (float)c.h; }
DEV f16x8 as_f16x8(short8 s){ union{short8 s; f16x8 h;} c; c.s = s; return c.h; }
DEV float fexp2(float x){
#if __has_builtin(__builtin_amdgcn_exp2f)
  return __builtin_amdgcn_exp2f(x);
#else
  return exp2f(x);
#endif
}
DEV float frcp(float x){
#if __has_builtin(__builtin_amdgcn_rcpf)
  return __builtin_amdgcn_rcpf(x);
#else
  return 1.f/x;
#endif
}
DEV float wsum(float v){
  #pragma unroll
  for(int o=32;o;o>>=1) v += __shfl_xor(v,o,64);
  return v;
}
DEV float wmax_(float v){
  #pragma unroll
  for(int o=32;o;o>>=1) v = fmaxf(v,__shfl_xor(v,o,64));
  return v;
}
// XOR swizzle for [rows][32 fp16] LDS tiles, row stride 64B, 16B units.
DEV int swz(int row, int unit){ return row*64 + ((unit ^ ((row>>1)&3))<<4); }

// ---------------- prep: W_gates fp32 -> fp16 bt-layout [n][g*256+k][h] -----------
__global__ __launch_bounds__(256) void prep_wbt(const float* __restrict__ W,
    const float* __restrict__ BG, unsigned short* __restrict__ WBT, float* __restrict__ BIAS){
  int bid = blockIdx.x;                 // (g,n,k) row-major, 4096 blocks
  int g = bid>>10, n = (bid>>8)&3, k = bid&255;
  int C = g*256 + k;
  int h = threadIdx.x;
  WBT[((size_t)n*1024 + C)*256 + h] = f2h(W[(size_t)bid*256 + h]);
  if (h==0) BIAS[n*1024 + C] = BG[(g*4+n)*256 + k];
}

// ---------------- prep: R_gates fp32 -> int8 fragment layout + per-col scales ----
__global__ __launch_bounds__(256) void prep_rq(const float* __restrict__ R,
    signed char* __restrict__ RQ, float* __restrict__ SC){
  int bid = blockIdx.x;                 // (g,n,k)
  int g = bid>>10, n = (bid>>8)&3, k = bid&255;
  int h = threadIdx.x;
  float v = R[(size_t)bid*256 + h];
  float a = fabsf(v);
  float m = wmax_(a);
  __shared__ float red[4];
  int wv = threadIdx.x>>6, l = threadIdx.x&63;
  if (!l) red[wv] = m;
  __syncthreads();
  m = fmaxf(fmaxf(red[0],red[1]), fmaxf(red[2],red[3]));
  float s = fmaxf(m, 1e-20f) * (1.f/127.f);
  int q = (int)rintf(v/s);
  q = q > 127 ? 127 : (q < -127 ? -127 : q);
  int w  = k>>5, kblk = (k>>4)&1, f = (kblk<<2)|g, kf = h>>6;
  int ln = (k&15) | (((h>>4)&3)<<4);
  int j  = h&15;
  RQ[ (((size_t)(n*8+w)*32 + (f*4+kf))*64 + ln)*16 + j ] = (signed char)q;
  if (h==0) SC[n*1024 + g*256 + k] = s * (1.f/127.f);
}

// ---------------- prep: transpose fp32 [K][N] -> fp16 [N][K] ----------------------
__global__ __launch_bounds__(256) void transpose_cast(const float* __restrict__ IN,
    unsigned short* __restrict__ OUT, int K, int N){
  __shared__ float tile[32][33];
  int n0 = blockIdx.x*32, k0 = blockIdx.y*32;
  int c = threadIdx.x&31, r4 = threadIdx.x>>5;
  #pragma unroll
  for (int rr = r4; rr < 32; rr += 8) tile[rr][c] = IN[(size_t)(k0+rr)*N + n0 + c];
  __syncthreads();
  #pragma unroll
  for (int rr = r4; rr < 32; rr += 8) OUT[(size_t)(n0+rr)*K + k0 + c] = f2h(tile[c][rr]);
}

// ---------------- rmsnorm fp32 -> fp16 (rms1) -------------------------------------
__global__ __launch_bounds__(256) void rmsnorm_k(const float* __restrict__ X,
    const float* __restrict__ W, unsigned short* __restrict__ O){
  size_t row = blockIdx.x;
  const f32x4* xp = (const f32x4*)(X + row*1024);
  f32x4 v = xp[threadIdx.x];
  float s = v[0]*v[0]+v[1]*v[1]+v[2]*v[2]+v[3]*v[3];
  s = wsum(s);
  __shared__ float red[4];
  int wv = threadIdx.x>>6, l = threadIdx.x&63;
  if (!l) red[wv] = s;
  __syncthreads();
  float tot = red[0]+red[1]+red[2]+red[3];
  float rs = rsqrtf(tot*(1.f/1024.f) + 1e-6f);
  int c = threadIdx.x*4;
  u16x4 o;
  #pragma unroll
  for (int j=0;j<4;j++) o[j] = f2h(v[j]*rs*W[c+j]);
  *(u16x4*)(O + row*1024 + c) = o;
}

// ---------------- gate GEMM, 128x128 tile -----------------------------------------
__global__ __launch_bounds__(256,2) void gemm0_k(
    const unsigned short* __restrict__ A, const unsigned short* __restrict__ B1,
    unsigned short* __restrict__ OB, const float* __restrict__ BIAS){
  __shared__ __align__(16) char smA[128*64];
  __shared__ __align__(16) char smB[128*64];
  int tid = threadIdx.x, w = tid>>6, l = tid&63;
  int n0 = blockIdx.x*128, m0 = blockIdx.y*128, head = blockIdx.z;
  A += (size_t)head*256; B1 += (size_t)head*1024*256;
  f32x4 acc[4][4];
  f32x4 z = {0.f,0.f,0.f,0.f};
  #pragma unroll
  for (int mi=0;mi<4;mi++)
    #pragma unroll
    for (int ni=0;ni<4;ni++) acc[mi][ni]=z;
  int wr = w>>1, wc = w&1;
  for (int kt = 0; kt < 256; kt += 32){
    #pragma unroll
    for (int c2=0;c2<2;c2++){
      int p = c2*256 + tid;
      int rr = p>>2, u = (p&3) ^ ((rr>>1)&3);
      int ldsb = (c2*256 + w*64)*16;
      GLOAD16(A  + (size_t)(m0+rr)*1024 + kt + u*8, smA + ldsb);
      GLOAD16(B1 + (size_t)(n0+rr)*256  + kt + u*8, smB + ldsb);
    }
    __syncthreads();
    short8 af[4], bf[4];
    #pragma unroll
    for (int mi=0;mi<4;mi++) af[mi] = *(const short8*)(smA + swz(wr*64 + mi*16 + (l&15), l>>4));
    #pragma unroll
    for (int ni=0;ni<4;ni++) bf[ni] = *(const short8*)(smB + swz(wc*64 + ni*16 + (l&15), l>>4));
    #pragma unroll
    for (int mi=0;mi<4;mi++)
      #pragma unroll
      for (int ni=0;ni<4;ni++)
        acc[mi][ni] = __builtin_amdgcn_mfma_f32_16x16x32_f16(as_f16x8(af[mi]), as_f16x8(bf[ni]), acc[mi][ni], 0,0,0);
    __syncthreads();
  }
  int rbase = m0 + wr*64, cbase = n0 + wc*64;
  #pragma unroll
  for (int mi=0;mi<4;mi++)
    #pragma unroll
    for (int ni=0;ni<4;ni++)
      #pragma unroll
      for (int j=0;j<4;j++){
        int gr = rbase + mi*16 + (l>>4)*4 + j;
        int gc = cbase + ni*16 + (l&15);
        int t = gr & 2047, b = gr >> 11;
        int g = gc >> 8, k = gc & 255;
        float fac = (g==2) ? 2.8853900817779268f : 1.4426950408889634f;
        OB[ (((size_t)t*4 + head)*256 + k)*32 + (b>>1)*8 + (b&1)*4 + g ]
          = f2h((acc[mi][ni][j] + BIAS[head*1024 + gc]) * fac);
      }
}

// ================== MEGA kernel: scan (WG 0-7) + downstream workers (WG 8-255) ====
// LDS padded to 86 KB so only ONE 16-wave WG fits per CU (2x86KB > 160KB):
// guarantees the 8 scan WGs never share a CU with workers (round-12 regression:
// 33KB LDS allowed 2 WGs/CU -> scan waves lost every-other issue slot, 3.7x slower).
#define SCAN_STEP(HR, HW, GXV, TT) do{                                          \
    i32x4 af[4];                                                                \
    _Pragma("unroll")                                                           \
    for (int kf=0;kf<4;kf++) af[kf] = *(const i32x4*)(&HR[ra + kf*64]);         \
    i32x4 acc[4];                                                               \
    _Pragma("unroll")                                                           \
    for (int g=0; g<4; g++){                                                    \
      i32x4 a = {0,0,0,0};                                                      \
      _Pragma("unroll")                                                         \
      for (int kf=0; kf<4; kf++)                                                \
        a = __builtin_amdgcn_mfma_i32_16x16x64_i8(af[kf], wf[g][kf], a, 0,0,0); \
      acc[g] = a;                                                               \
    }                                                                           \
    float ip2 = fmaf(sch[0],(float)acc[0][0], fmaf(scl[0],(float)acc[0][1], h2f(GXV[0]))); \
    float fpv = fmaf(sch[1],(float)acc[1][0], fmaf(scl[1],(float)acc[1][1], h2f(GXV[1]))) + ms; \
    float zp2 = fmaf(sch[2],(float)acc[2][0], fmaf(scl[2],(float)acc[2][1], h2f(GXV[2]))); \
    float op2 = fmaf(sch[3],(float)acc[3][0], fmaf(scl[3],(float)acc[3][1], h2f(GXV[3]))); \
    float mn = fmaxf(fpv, ip2);                                                 \
    float ig = fexp2(ip2 - mn);                                                 \
    float fg = fexp2(fpv - mn);                                                 \
    float e2 = fexp2(zp2);                                                      \
    float tz = fmaf(-2.f, frcp(e2 + 1.f), 1.f);                                 \
    float eo = fexp2(-op2);                                                     \
    float c  = fmaf(ig, tz, fg*cs);                                             \
    float nn = fmaf(fg, ns_, ig);                                               \
    float h  = c * frcp((1.f + eo)*nn);                                         \
    cs=c; ns_=nn; ms=mn;                                                        \
    float h127 = h*127.f;                                                       \
    float hiq = rintf(h127);                                                    \
    float loq = rintf((h127 - hiq)*127.f);                                      \
    HW[r_hi] = (signed char)(int)hiq;                                           \
    HW[r_lo] = (signed char)(int)loq;                                           \
    HS[(size_t)(TT)*8192 + hoff] = f2h(h);                                      \
  }while(0)

DEV void sig_wait(int* f, int tid){
  asm volatile("s_waitcnt vmcnt(0) lgkmcnt(0)" ::: "memory");
  __syncthreads();
  if (tid==0){
    __hip_atomic_fetch_add(f, 1, __ATOMIC_RELEASE, __HIP_MEMORY_SCOPE_AGENT);
    while (__hip_atomic_load(f, __ATOMIC_ACQUIRE, __HIP_MEMORY_SCOPE_AGENT) < 248)
      __builtin_amdgcn_s_sleep(2);
  }
  __syncthreads();
}

__global__ __launch_bounds__(1024) void mega_k(
    const unsigned short* GX, const signed char* RQ, const float* SC,
    unsigned short* HS, int* FLAGS,
    const float* X, const float* GNW, const float* LN2W,
    const unsigned short* WGT, const unsigned short* WUT, const unsigned short* WDT,
    char* CHUNK0, float* X2OUT){
  __shared__ __align__(16) char smem[86016];   // >80KB -> exclusive CU occupancy
  int tid = threadIdx.x;
  const float L2E = 1.44269504f;

  if (blockIdx.x < 8){
    // ---------------- scan path (unchanged core) ----------------
    int bid = blockIdx.x;
    int n = bid >> 1, bg = bid & 1;
    int w = tid>>6, l = tid&63;
    signed char* hlA = (signed char*)smem;
    signed char* hlB = (signed char*)(smem + 4352);
    for (int i = tid; i < 8704; i += 1024) smem[i] = 0;

    int l15 = l & 15, q = l >> 4;
    i32x4 wf[4][4];
    {
      const i32x4* rp = (const i32x4*)RQ + (size_t)(n*8 + (w>>1))*32*64;
      #pragma unroll
      for (int g=0; g<4; g++){
        int f = ((w&1)<<2) | g;
        #pragma unroll
        for (int kf=0; kf<4; kf++)
          wf[g][kf] = rp[(f*4+kf)*64 + l];
      }
    }
    float sch[4], scl[4];
    {
      const float facs[4] = {1.4426950408889634f, 1.4426950408889634f,
                             2.8853900817779268f, 1.4426950408889634f};
      #pragma unroll
      for (int g=0; g<4; g++){
        float s = SC[n*1024 + g*256 + w*16 + l15] * facs[g];
        sch[g] = s; scl[g] = s*(1.f/127.f);
      }
    }
    float cs = 0.f, ns_ = 0.f, ms = 0.f;
    int goff = (n*256 + w*16 + l15)*32 + (bg*2 + (q>>1))*8 + (q&1)*4;
    int hoff = (n*8 + bg*4 + q)*256 + w*16 + l15;
    int ra   = l15*272 + q*16;
    int r_hi = (4*q + 0)*272 + w*16 + l15;
    int r_lo = r_hi + 272;

    u16x4 gxr = *(const u16x4*)(GX + goff);
    __syncthreads();

    for (int t = 0; t < 2048; t += 2){
      u16x4 gx1 = *(const u16x4*)(GX + (size_t)(t+1)*32768 + goff);
      SCAN_STEP(hlA, hlB, gxr, t);
      asm volatile("s_waitcnt lgkmcnt(0)" ::: "memory");
      __builtin_amdgcn_s_barrier();
      __builtin_amdgcn_sched_barrier(0);
      int tt2 = (t+2 < 2048) ? (t+2) : 2047;
      gxr = *(const u16x4*)(GX + (size_t)tt2*32768 + goff);
      SCAN_STEP(hlB, hlA, gx1, t+1);
      asm volatile("s_waitcnt lgkmcnt(0)" ::: "memory");
      __builtin_amdgcn_s_barrier();
      __builtin_amdgcn_sched_barrier(0);
      if (((t+2) & 255) == 0){
        asm volatile("s_waitcnt vmcnt(0)" ::: "memory");
        __builtin_amdgcn_s_barrier();
        if (tid == 0)
          __hip_atomic_fetch_add(&FLAGS[(t+1)>>8], 1, __ATOMIC_RELEASE, __HIP_MEMORY_SCOPE_AGENT);
      }
    }
  } else {
    // ---------------- worker path ----------------
    int wid = blockIdx.x - 8;               // 0..247
    int w = tid>>6, l = tid&63;
    int wr = w>>2, wc = w&3;
    char* smA  = smem;
    char* smB  = smem + 16384;
    char* smB2 = smem + 24576;
    float* red = (float*)(smem + 32768);

    for (int c = 0; c < 8; ++c){
      char* cb = CHUNK0 + (size_t)c*16777216;
      unsigned short* y2c = (unsigned short*)cb;
      unsigned short* Sc  = (unsigned short*)(cb + 4194304);

      if (tid==0){
        while (__hip_atomic_load(&FLAGS[c], __ATOMIC_ACQUIRE, __HIP_MEMORY_SCOPE_AGENT) < 8)
          __builtin_amdgcn_s_sleep(2);
      }
      __syncthreads();

      // ---- stage N: x2 = x + LN(hs)*gnw ; y2c = rmsnorm(x2)*ln2w ----
      {
        int hn = tid>>8, hk = tid&255;
        for (int r = wid; r < 2048; r += 248){
          int b = r>>8, tl = r&255, t = c*256 + tl;
          float v = h2f(HS[(((size_t)t*4+hn)*8+b)*256 + hk]);
          float s1 = wsum(v), s2 = wsum(v*v);
          if (!(tid&63)){ red[tid>>6] = s1; red[16+(tid>>6)] = s2; }
          __syncthreads();
          float sum = 0.f, sq = 0.f;
          #pragma unroll
          for (int i=0;i<4;i++){ sum += red[hn*4+i]; sq += red[16+hn*4+i]; }
          float mu = sum*(1.f/256.f);
          float var = sq*(1.f/256.f) - mu*mu;
          float rs = rsqrtf(var + 1e-5f);
          size_t xi = (size_t)(b*2048+t)*1024 + tid;
          float x2v = X[xi] + (v-mu)*rs*GNW[tid];
          X2OUT[xi] = x2v;
          float qq = wsum(x2v*x2v);
          if (!(tid&63)) red[32+(tid>>6)] = qq;
          __syncthreads();
          float tot = 0.f;
          #pragma unroll
          for (int i=0;i<16;i++) tot += red[32+i];
          float rs2 = rsqrtf(tot*(1.f/1024.f) + 1e-6f);
          y2c[(size_t)r*1024 + tid] = f2h(x2v*rs2*LN2W[tid]);
          __syncthreads();
        }
      }
      sig_wait(&FLAGS[8+c], tid);

      // ---- stage G1: S = silu(y2c@Wg^T) * (y2c@Wu^T), 256x128 tiles ----
      for (int task = wid; task < 176; task += 248){
        int mt = task/22, nt = task - mt*22;
        const unsigned short* A  = y2c + (size_t)mt*256*1024;
        const unsigned short* B1 = WGT + (size_t)nt*128*1024;
        const unsigned short* B2 = WUT + (size_t)nt*128*1024;
        f32x4 acc[4][2], acc2[4][2];
        f32x4 z = {0.f,0.f,0.f,0.f};
        #pragma unroll
        for (int mi=0;mi<4;mi++)
          #pragma unroll
          for (int ni=0;ni<2;ni++){ acc[mi][ni]=z; acc2[mi][ni]=z; }
        int pA = w*64 + l, rA = pA>>2, uA = (pA&3)^((rA>>1)&3);
        int w8 = w & 7;
        int pB = w8*64 + l, rB = pB>>2, uB = (pB&3)^((rB>>1)&3);
        for (int kt = 0; kt < 1024; kt += 32){
          GLOAD16(A + (size_t)rA*1024 + kt + uA*8, smA + w*1024);
          if (w < 8) GLOAD16(B1 + (size_t)rB*1024 + kt + uB*8, smB  + w8*1024);
          else       GLOAD16(B2 + (size_t)rB*1024 + kt + uB*8, smB2 + w8*1024);
          __syncthreads();
          short8 af[4], bf[2], bg[2];
          #pragma unroll
          for (int mi=0;mi<4;mi++) af[mi] = *(const short8*)(smA + swz(wr*64 + mi*16 + (l&15), l>>4));
          #pragma unroll
          for (int ni=0;ni<2;ni++){
            bf[ni] = *(const short8*)(smB  + swz(wc*32 + ni*16 + (l&15), l>>4));
            bg[ni] = *(const short8*)(smB2 + swz(wc*32 + ni*16 + (l&15), l>>4));
          }
          #pragma unroll
          for (int mi=0;mi<4;mi++)
            #pragma unroll
            for (int ni=0;ni<2;ni++){
              acc[mi][ni]  = __builtin_amdgcn_mfma_f32_16x16x32_f16(as_f16x8(af[mi]), as_f16x8(bf[ni]), acc[mi][ni], 0,0,0);
              acc2[mi][ni] = __builtin_amdgcn_mfma_f32_16x16x32_f16(as_f16x8(af[mi]), as_f16x8(bg[ni]), acc2[mi][ni], 0,0,0);
            }
          __syncthreads();
        }
        #pragma unroll
        for (int mi=0;mi<4;mi++)
          #pragma unroll
          for (int ni=0;ni<2;ni++)
            #pragma unroll
            for (int j=0;j<4;j++){
              int gr = wr*64 + mi*16 + (l>>4)*4 + j;
              int gc = nt*128 + wc*32 + ni*16 + (l&15);
              if (gc < 2752){
                float v = acc[mi][ni][j], u2 = acc2[mi][ni][j];
                float sg = v*frcp(1.f + fexp2(-v*L2E));
                Sc[(size_t)(mt*256+gr)*2752 + gc] = f2h(sg*u2);
              }
            }
      }
      sig_wait(&FLAGS[16+c], tid);

      // ---- stage G2: out = x2 + S@Wd^T, 256x128 tiles ----
      for (int task = wid; task < 64; task += 248){
        int mt = task>>3, nt = task&7;
        const unsigned short* A = Sc  + (size_t)mt*256*2752;
        const unsigned short* B = WDT + (size_t)nt*128*2752;
        f32x4 acc[4][2];
        f32x4 z = {0.f,0.f,0.f,0.f};
        #pragma unroll
        for (int mi=0;mi<4;mi++)
          #pragma unroll
          for (int ni=0;ni<2;ni++) acc[mi][ni]=z;
        int pA = w*64 + l, rA = pA>>2, uA = (pA&3)^((rA>>1)&3);
        int w8 = w & 7;
        int pB = w8*64 + l, rB = pB>>2, uB = (pB&3)^((rB>>1)&3);
        for (int kt = 0; kt < 2752; kt += 32){
          GLOAD16(A + (size_t)rA*2752 + kt + uA*8, smA + w*1024);
          if (w < 8) GLOAD16(B + (size_t)rB*2752 + kt + uB*8, smB + w8*1024);
          __syncthreads();
          short8 af[4], bf[2];
          #pragma unroll
          for (int mi=0;mi<4;mi++) af[mi] = *(const short8*)(smA + swz(wr*64 + mi*16 + (l&15), l>>4));
          #pragma unroll
          for (int ni=0;ni<2;ni++) bf[ni] = *(const short8*)(smB + swz(wc*32 + ni*16 + (l&15), l>>4));
          #pragma unroll
          for (int mi=0;mi<4;mi++)
            #pragma unroll
            for (int ni=0;ni<2;ni++)
              acc[mi][ni] = __builtin_amdgcn_mfma_f32_16x16x32_f16(as_f16x8(af[mi]), as_f16x8(bf[ni]), acc[mi][ni], 0,0,0);
          __syncthreads();
        }
        #pragma unroll
        for (int mi=0;mi<4;mi++)
          #pragma unroll
          for (int ni=0;ni<2;ni++)
            #pragma unroll
            for (int j=0;j<4;j++){
              int gr = wr*64 + mi*16 + (l>>4)*4 + j;
              int gc = nt*128 + wc*32 + ni*16 + (l&15);
              size_t idx = (size_t)(mt*2048 + c*256 + gr)*1024 + gc;
              X2OUT[idx] = X2OUT[idx] + acc[mi][ni][j];
            }
      }
      sig_wait(&FLAGS[24+c], tid);
    }
  }
}

// ---------------- launch ----------------------------------------------------------
extern "C" void kernel_launch(void* const* d_in, const int* in_sizes, int n_in,
                              void* d_out, int out_size, void* d_ws, size_t ws_size,
                              hipStream_t stream){
  (void)in_sizes; (void)n_in; (void)out_size;
  const float* x    = (const float*)d_in[0];
  const float* ln1w = (const float*)d_in[1];
  const float* Wg_  = (const float*)d_in[2];
  const float* Rg_  = (const float*)d_in[3];
  const float* bg_  = (const float*)d_in[4];
  const float* gnw  = (const float*)d_in[5];
  const float* ln2w = (const float*)d_in[6];
  const float* Wgf  = (const float*)d_in[7];
  const float* Wuf  = (const float*)d_in[8];
  const float* Wdf  = (const float*)d_in[9];
  float* out = (float*)d_out;
  char* ws = (char*)d_ws;

  // workspace layout (total 187,858,944 B):
  //   [0..20.1M)   persistent weights (wbt,bias,rq,sc2,wgt,wut,wdt)
  //                bias region doubles as FLAGS after gemm0 (bias dead)
  //   [20.1M..53.6M)  xn (rms1 out) -> hs (scan out)
  //   [53.6M..187.9M) gx; per-chunk scratch (y2c+Sc) reuses gx chunk c's own
  //                   16MB region (fully consumed before FLAGS[c] publishes)
  //   x2 lives in d_out (fully rewritten each launch)
  if (ws_size < 187858944ull) return;
  unsigned short* wbt = (unsigned short*)(ws + 0);
  float*          bias= (float*)        (ws + 2097152);
  int*            flags=(int*)          (ws + 2097152);   // aliases bias (dead post-gemm0)
  signed char*    rq  = (signed char*)  (ws + 2113536);
  float*          sc2 = (float*)        (ws + 3162112);
  unsigned short* wgt = (unsigned short*)(ws + 3178496);
  unsigned short* wut = (unsigned short*)(ws + 8814592);
  unsigned short* wdt = (unsigned short*)(ws + 14450688);
  unsigned short* xn  = (unsigned short*)(ws + 20086784);
  unsigned short* hs  = (unsigned short*)(ws + 20086784);  // aliases xn
  unsigned short* gx  = (unsigned short*)(ws + 53641216);

  prep_wbt<<<4096,256,0,stream>>>(Wg_, bg_, wbt, bias);
  prep_rq <<<4096,256,0,stream>>>(Rg_, rq, sc2);
  transpose_cast<<<dim3(86,32),256,0,stream>>>(Wgf, wgt, 1024, 2752);
  transpose_cast<<<dim3(86,32),256,0,stream>>>(Wuf, wut, 1024, 2752);
  transpose_cast<<<dim3(32,86),256,0,stream>>>(Wdf, wdt, 2752, 1024);

  rmsnorm_k<<<16384,256,0,stream>>>(x, ln1w, xn);
  gemm0_k<<<dim3(8,128,4),256,0,stream>>>(xn, wbt, gx, bias);
  hipMemsetAsync(flags, 0, 128, stream);
  mega_k<<<256,1024,0,stream>>>(gx, rq, sc2, hs, flags, x, gnw, ln2w,
                                wgt, wut, wdt, (char*)gx, out);
}

// Round 14
// 5302.309 us; speedup vs baseline: 1.1864x; 1.1864x over previous
//
#include <hip/hip_runtime.h>
#include <hip/hip_bf16.h>

#define DEV __device__ __forceinline__

typedef __attribute__((ext_vector_type(4))) float f32x4;
typedef __attribute__((ext_vector_type(8))) short short8;
typedef __attribute__((ext_vector_type(8))) _Float16 f16x8;
typedef __attribute__((ext_vector_type(4))) int i32x4;
typedef __attribute__((ext_vector_type(4))) unsigned short u16x4;

typedef __attribute__((address_space(3))) void lds_void;
typedef const __attribute__((address_space(1))) void g_void;
#define GLOAD16(g, l) __builtin_amdgcn_global_load_lds((g_void*)(g), (lds_void*)(l), 16, 0, 0)

DEV unsigned short f2h(float f){ union{_Float16 h; unsigned short u;} c; c.h = (_Float16)f; return c.u; }
DEV float h2f(unsigned short u){ union{unsigned short u; _Float16 h;} c; c.u = u; return (float)c.h; }
DEV f16x8 as_f16x8(short8 s){ union{short8 s; f16x8 h;} c; c.s = s; return c.h; }
DEV float fexp2(float x){
#if __has_builtin(__builtin_amdgcn_exp2f)
  return __builtin_amdgcn_exp2f(x);
#else
  return exp2f(x);
#endif
}
DEV float frcp(float x){
#if __has_builtin(__builtin_amdgcn_rcpf)
  return __builtin_amdgcn_rcpf(x);
#else
  return 1.f/x;
#endif
}
DEV float wsum(float v){
  #pragma unroll
  for(int o=32;o;o>>=1) v += __shfl_xor(v,o,64);
  return v;
}
DEV float wmax_(float v){
  #pragma unroll
  for(int o=32;o;o>>=1) v = fmaxf(v,__shfl_xor(v,o,64));
  return v;
}
// XOR swizzle for [rows][32 fp16] LDS tiles, row stride 64B, 16B units.
DEV int swz(int row, int unit){ return row*64 + ((unit ^ ((row>>1)&3))<<4); }

// ---------------- prep: W_gates fp32 -> fp16 bt-layout [n][g*256+k][h] -----------
__global__ __launch_bounds__(256) void prep_wbt(const float* __restrict__ W,
    const float* __restrict__ BG, unsigned short* __restrict__ WBT, float* __restrict__ BIAS){
  int bid = blockIdx.x;                 // (g,n,k) row-major, 4096 blocks
  int g = bid>>10, n = (bid>>8)&3, k = bid&255;
  int C = g*256 + k;
  int h = threadIdx.x;
  WBT[((size_t)n*1024 + C)*256 + h] = f2h(W[(size_t)bid*256 + h]);
  if (h==0) BIAS[n*1024 + C] = BG[(g*4+n)*256 + k];
}

// ---------------- prep: R_gates fp32 -> int8 fragment layout + per-col scales ----
__global__ __launch_bounds__(256) void prep_rq(const float* __restrict__ R,
    signed char* __restrict__ RQ, float* __restrict__ SC){
  int bid = blockIdx.x;                 // (g,n,k)
  int g = bid>>10, n = (bid>>8)&3, k = bid&255;
  int h = threadIdx.x;
  float v = R[(size_t)bid*256 + h];
  float a = fabsf(v);
  float m = wmax_(a);
  __shared__ float red[4];
  int wv = threadIdx.x>>6, l = threadIdx.x&63;
  if (!l) red[wv] = m;
  __syncthreads();
  m = fmaxf(fmaxf(red[0],red[1]), fmaxf(red[2],red[3]));
  float s = fmaxf(m, 1e-20f) * (1.f/127.f);
  int q = (int)rintf(v/s);
  q = q > 127 ? 127 : (q < -127 ? -127 : q);
  int w  = k>>5, kblk = (k>>4)&1, f = (kblk<<2)|g, kf = h>>6;
  int ln = (k&15) | (((h>>4)&3)<<4);
  int j  = h&15;
  RQ[ (((size_t)(n*8+w)*32 + (f*4+kf))*64 + ln)*16 + j ] = (signed char)q;
  if (h==0) SC[n*1024 + g*256 + k] = s * (1.f/127.f);
}

// ---------------- prep: transpose fp32 [K][N] -> fp16 [N][K] ----------------------
__global__ __launch_bounds__(256) void transpose_cast(const float* __restrict__ IN,
    unsigned short* __restrict__ OUT, int K, int N){
  __shared__ float tile[32][33];
  int n0 = blockIdx.x*32, k0 = blockIdx.y*32;
  int c = threadIdx.x&31, r4 = threadIdx.x>>5;
  #pragma unroll
  for (int rr = r4; rr < 32; rr += 8) tile[rr][c] = IN[(size_t)(k0+rr)*N + n0 + c];
  __syncthreads();
  #pragma unroll
  for (int rr = r4; rr < 32; rr += 8) OUT[(size_t)(n0+rr)*K + k0 + c] = f2h(tile[c][rr]);
}

// ---------------- rmsnorm fp32 -> fp16 (rms1) -------------------------------------
__global__ __launch_bounds__(256) void rmsnorm_k(const float* __restrict__ X,
    const float* __restrict__ W, unsigned short* __restrict__ O){
  size_t row = blockIdx.x;
  const f32x4* xp = (const f32x4*)(X + row*1024);
  f32x4 v = xp[threadIdx.x];
  float s = v[0]*v[0]+v[1]*v[1]+v[2]*v[2]+v[3]*v[3];
  s = wsum(s);
  __shared__ float red[4];
  int wv = threadIdx.x>>6, l = threadIdx.x&63;
  if (!l) red[wv] = s;
  __syncthreads();
  float tot = red[0]+red[1]+red[2]+red[3];
  float rs = rsqrtf(tot*(1.f/1024.f) + 1e-6f);
  int c = threadIdx.x*4;
  u16x4 o;
  #pragma unroll
  for (int j=0;j<4;j++) o[j] = f2h(v[j]*rs*W[c+j]);
  *(u16x4*)(O + row*1024 + c) = o;
}

// ---------------- gate GEMM, 128x128 tile -----------------------------------------
__global__ __launch_bounds__(256,2) void gemm0_k(
    const unsigned short* __restrict__ A, const unsigned short* __restrict__ B1,
    unsigned short* __restrict__ OB, const float* __restrict__ BIAS){
  __shared__ __align__(16) char smA[128*64];
  __shared__ __align__(16) char smB[128*64];
  int tid = threadIdx.x, w = tid>>6, l = tid&63;
  int n0 = blockIdx.x*128, m0 = blockIdx.y*128, head = blockIdx.z;
  A += (size_t)head*256; B1 += (size_t)head*1024*256;
  f32x4 acc[4][4];
  f32x4 z = {0.f,0.f,0.f,0.f};
  #pragma unroll
  for (int mi=0;mi<4;mi++)
    #pragma unroll
    for (int ni=0;ni<4;ni++) acc[mi][ni]=z;
  int wr = w>>1, wc = w&1;
  for (int kt = 0; kt < 256; kt += 32){
    #pragma unroll
    for (int c2=0;c2<2;c2++){
      int p = c2*256 + tid;
      int rr = p>>2, u = (p&3) ^ ((rr>>1)&3);
      int ldsb = (c2*256 + w*64)*16;
      GLOAD16(A  + (size_t)(m0+rr)*1024 + kt + u*8, smA + ldsb);
      GLOAD16(B1 + (size_t)(n0+rr)*256  + kt + u*8, smB + ldsb);
    }
    __syncthreads();
    short8 af[4], bf[4];
    #pragma unroll
    for (int mi=0;mi<4;mi++) af[mi] = *(const short8*)(smA + swz(wr*64 + mi*16 + (l&15), l>>4));
    #pragma unroll
    for (int ni=0;ni<4;ni++) bf[ni] = *(const short8*)(smB + swz(wc*64 + ni*16 + (l&15), l>>4));
    #pragma unroll
    for (int mi=0;mi<4;mi++)
      #pragma unroll
      for (int ni=0;ni<4;ni++)
        acc[mi][ni] = __builtin_amdgcn_mfma_f32_16x16x32_f16(as_f16x8(af[mi]), as_f16x8(bf[ni]), acc[mi][ni], 0,0,0);
    __syncthreads();
  }
  int rbase = m0 + wr*64, cbase = n0 + wc*64;
  #pragma unroll
  for (int mi=0;mi<4;mi++)
    #pragma unroll
    for (int ni=0;ni<4;ni++)
      #pragma unroll
      for (int j=0;j<4;j++){
        int gr = rbase + mi*16 + (l>>4)*4 + j;
        int gc = cbase + ni*16 + (l&15);
        int t = gr & 2047, b = gr >> 11;
        int g = gc >> 8, k = gc & 255;
        float fac = (g==2) ? 2.8853900817779268f : 1.4426950408889634f;
        OB[ (((size_t)t*4 + head)*256 + k)*32 + (b>>1)*8 + (b&1)*4 + g ]
          = f2h((acc[mi][ni][j] + BIAS[head*1024 + gc]) * fac);
      }
}

// ================== MEGA kernel: scan (WG 0-7) + downstream workers (WG 8-255) ====
// launch_bounds(1024,4): 4 waves/EU -> 128-VGPR cap. Round 12/13 regression was the
// default 64-VGPR cap spilling the worker GEMM accumulators to scratch (~10x).
// Worker tiles slimmed to 256x64 (4x4 wave grid, wave-tile 64x16) -> ~85 live VGPRs.
#define SCAN_STEP(HR, HW, GXV, TT) do{                                          \
    i32x4 af[4];                                                                \
    _Pragma("unroll")                                                           \
    for (int kf=0;kf<4;kf++) af[kf] = *(const i32x4*)(&HR[ra + kf*64]);         \
    i32x4 acc[4];                                                               \
    _Pragma("unroll")                                                           \
    for (int g=0; g<4; g++){                                                    \
      i32x4 a = {0,0,0,0};                                                      \
      _Pragma("unroll")                                                         \
      for (int kf=0; kf<4; kf++)                                                \
        a = __builtin_amdgcn_mfma_i32_16x16x64_i8(af[kf], wf[g][kf], a, 0,0,0); \
      acc[g] = a;                                                               \
    }                                                                           \
    float ip2 = fmaf(sch[0],(float)acc[0][0], fmaf(scl[0],(float)acc[0][1], h2f(GXV[0]))); \
    float fpv = fmaf(sch[1],(float)acc[1][0], fmaf(scl[1],(float)acc[1][1], h2f(GXV[1]))) + ms; \
    float zp2 = fmaf(sch[2],(float)acc[2][0], fmaf(scl[2],(float)acc[2][1], h2f(GXV[2]))); \
    float op2 = fmaf(sch[3],(float)acc[3][0], fmaf(scl[3],(float)acc[3][1], h2f(GXV[3]))); \
    float mn = fmaxf(fpv, ip2);                                                 \
    float ig = fexp2(ip2 - mn);                                                 \
    float fg = fexp2(fpv - mn);                                                 \
    float e2 = fexp2(zp2);                                                      \
    float tz = fmaf(-2.f, frcp(e2 + 1.f), 1.f);                                 \
    float eo = fexp2(-op2);                                                     \
    float c  = fmaf(ig, tz, fg*cs);                                             \
    float nn = fmaf(fg, ns_, ig);                                               \
    float h  = c * frcp((1.f + eo)*nn);                                         \
    cs=c; ns_=nn; ms=mn;                                                        \
    float h127 = h*127.f;                                                       \
    float hiq = rintf(h127);                                                    \
    float loq = rintf((h127 - hiq)*127.f);                                      \
    HW[r_hi] = (signed char)(int)hiq;                                           \
    HW[r_lo] = (signed char)(int)loq;                                           \
    HS[(size_t)(TT)*8192 + hoff] = f2h(h);                                      \
  }while(0)

DEV void sig_wait(int* f, int tid){
  asm volatile("s_waitcnt vmcnt(0) lgkmcnt(0)" ::: "memory");
  __syncthreads();
  if (tid==0){
    __hip_atomic_fetch_add(f, 1, __ATOMIC_RELEASE, __HIP_MEMORY_SCOPE_AGENT);
    while (__hip_atomic_load(f, __ATOMIC_ACQUIRE, __HIP_MEMORY_SCOPE_AGENT) < 248)
      __builtin_amdgcn_s_sleep(2);
  }
  __syncthreads();
}

__global__ __launch_bounds__(1024,4) void mega_k(
    const unsigned short* GX, const signed char* RQ, const float* SC,
    unsigned short* HS, int* FLAGS,
    const float* X, const float* GNW, const float* LN2W,
    const unsigned short* WGT, const unsigned short* WUT, const unsigned short* WDT,
    char* CHUNK0, float* X2OUT){
  __shared__ __align__(16) char smem[86016];   // 1 WG/CU
  int tid = threadIdx.x;
  const float L2E = 1.44269504f;

  if (blockIdx.x < 8){
    // ---------------- scan path (unchanged core) ----------------
    int bid = blockIdx.x;
    int n = bid >> 1, bg = bid & 1;
    int w = tid>>6, l = tid&63;
    signed char* hlA = (signed char*)smem;
    signed char* hlB = (signed char*)(smem + 4352);
    for (int i = tid; i < 8704; i += 1024) smem[i] = 0;

    int l15 = l & 15, q = l >> 4;
    i32x4 wf[4][4];
    {
      const i32x4* rp = (const i32x4*)RQ + (size_t)(n*8 + (w>>1))*32*64;
      #pragma unroll
      for (int g=0; g<4; g++){
        int f = ((w&1)<<2) | g;
        #pragma unroll
        for (int kf=0; kf<4; kf++)
          wf[g][kf] = rp[(f*4+kf)*64 + l];
      }
    }
    float sch[4], scl[4];
    {
      const float facs[4] = {1.4426950408889634f, 1.4426950408889634f,
                             2.8853900817779268f, 1.4426950408889634f};
      #pragma unroll
      for (int g=0; g<4; g++){
        float s = SC[n*1024 + g*256 + w*16 + l15] * facs[g];
        sch[g] = s; scl[g] = s*(1.f/127.f);
      }
    }
    float cs = 0.f, ns_ = 0.f, ms = 0.f;
    int goff = (n*256 + w*16 + l15)*32 + (bg*2 + (q>>1))*8 + (q&1)*4;
    int hoff = (n*8 + bg*4 + q)*256 + w*16 + l15;
    int ra   = l15*272 + q*16;
    int r_hi = (4*q + 0)*272 + w*16 + l15;
    int r_lo = r_hi + 272;

    u16x4 gxr = *(const u16x4*)(GX + goff);
    __syncthreads();

    for (int t = 0; t < 2048; t += 2){
      u16x4 gx1 = *(const u16x4*)(GX + (size_t)(t+1)*32768 + goff);
      SCAN_STEP(hlA, hlB, gxr, t);
      asm volatile("s_waitcnt lgkmcnt(0)" ::: "memory");
      __builtin_amdgcn_s_barrier();
      __builtin_amdgcn_sched_barrier(0);
      int tt2 = (t+2 < 2048) ? (t+2) : 2047;
      gxr = *(const u16x4*)(GX + (size_t)tt2*32768 + goff);
      SCAN_STEP(hlB, hlA, gx1, t+1);
      asm volatile("s_waitcnt lgkmcnt(0)" ::: "memory");
      __builtin_amdgcn_s_barrier();
      __builtin_amdgcn_sched_barrier(0);
      if (((t+2) & 255) == 0){
        asm volatile("s_waitcnt vmcnt(0)" ::: "memory");
        __builtin_amdgcn_s_barrier();
        if (tid == 0)
          __hip_atomic_fetch_add(&FLAGS[(t+1)>>8], 1, __ATOMIC_RELEASE, __HIP_MEMORY_SCOPE_AGENT);
      }
    }
  } else {
    // ---------------- worker path ----------------
    int wid = blockIdx.x - 8;               // 0..247
    int w = tid>>6, l = tid&63;
    int wr = w>>2, wc = w&3;                 // 4x4 wave grid, wave tile 64x16
    char* smA  = smem;                       // 256x32 fp16 = 16KB
    char* smB  = smem + 16384;               // 64x32 fp16 = 4KB
    char* smB2 = smem + 20480;               // 64x32 fp16 = 4KB
    float* red = (float*)(smem + 32768);

    int pA = w*64 + l, rA = pA>>2, uA = (pA&3)^((rA>>1)&3);
    int w4 = w & 3;
    int pB = w4*64 + l, rB = pB>>2, uB = (pB&3)^((rB>>1)&3);

    for (int c = 0; c < 8; ++c){
      char* cb = CHUNK0 + (size_t)c*16777216;
      unsigned short* y2c = (unsigned short*)cb;
      unsigned short* Sc  = (unsigned short*)(cb + 4194304);

      if (tid==0){
        while (__hip_atomic_load(&FLAGS[c], __ATOMIC_ACQUIRE, __HIP_MEMORY_SCOPE_AGENT) < 8)
          __builtin_amdgcn_s_sleep(2);
      }
      __syncthreads();

      // ---- stage N: x2 = x + LN(hs)*gnw ; y2c = rmsnorm(x2)*ln2w ----
      {
        int hn = tid>>8, hk = tid&255;
        for (int r = wid; r < 2048; r += 248){
          int b = r>>8, tl = r&255, t = c*256 + tl;
          float v = h2f(HS[(((size_t)t*4+hn)*8+b)*256 + hk]);
          float s1 = wsum(v), s2 = wsum(v*v);
          if (!(tid&63)){ red[tid>>6] = s1; red[16+(tid>>6)] = s2; }
          __syncthreads();
          float sum = 0.f, sq = 0.f;
          #pragma unroll
          for (int i=0;i<4;i++){ sum += red[hn*4+i]; sq += red[16+hn*4+i]; }
          float mu = sum*(1.f/256.f);
          float var = sq*(1.f/256.f) - mu*mu;
          float rs = rsqrtf(var + 1e-5f);
          size_t xi = (size_t)(b*2048+t)*1024 + tid;
          float x2v = X[xi] + (v-mu)*rs*GNW[tid];
          X2OUT[xi] = x2v;
          float qq = wsum(x2v*x2v);
          if (!(tid&63)) red[32+(tid>>6)] = qq;
          __syncthreads();
          float tot = 0.f;
          #pragma unroll
          for (int i=0;i<16;i++) tot += red[32+i];
          float rs2 = rsqrtf(tot*(1.f/1024.f) + 1e-6f);
          y2c[(size_t)r*1024 + tid] = f2h(x2v*rs2*LN2W[tid]);
          __syncthreads();
        }
      }
      sig_wait(&FLAGS[8+c], tid);

      // ---- stage G1: S = silu(y2c@Wg^T) * (y2c@Wu^T), 256x64 tiles, 344 tasks ----
      for (int task = wid; task < 344; task += 248){
        int mt = task/43, nt = task - mt*43;
        const unsigned short* A  = y2c + (size_t)mt*256*1024;
        const unsigned short* B1 = WGT + (size_t)nt*64*1024;
        const unsigned short* B2 = WUT + (size_t)nt*64*1024;
        f32x4 acc[4], acc2[4];
        f32x4 z = {0.f,0.f,0.f,0.f};
        #pragma unroll
        for (int mi=0;mi<4;mi++){ acc[mi]=z; acc2[mi]=z; }
        for (int kt = 0; kt < 1024; kt += 32){
          GLOAD16(A + (size_t)rA*1024 + kt + uA*8, smA + w*1024);
          if (w < 4)      GLOAD16(B1 + (size_t)rB*1024 + kt + uB*8, smB  + w4*1024);
          else if (w < 8) GLOAD16(B2 + (size_t)rB*1024 + kt + uB*8, smB2 + w4*1024);
          __syncthreads();
          short8 af[4], bf, bg;
          #pragma unroll
          for (int mi=0;mi<4;mi++) af[mi] = *(const short8*)(smA + swz(wr*64 + mi*16 + (l&15), l>>4));
          bf = *(const short8*)(smB  + swz(wc*16 + (l&15), l>>4));
          bg = *(const short8*)(smB2 + swz(wc*16 + (l&15), l>>4));
          #pragma unroll
          for (int mi=0;mi<4;mi++){
            acc[mi]  = __builtin_amdgcn_mfma_f32_16x16x32_f16(as_f16x8(af[mi]), as_f16x8(bf), acc[mi], 0,0,0);
            acc2[mi] = __builtin_amdgcn_mfma_f32_16x16x32_f16(as_f16x8(af[mi]), as_f16x8(bg), acc2[mi], 0,0,0);
          }
          __syncthreads();
        }
        #pragma unroll
        for (int mi=0;mi<4;mi++)
          #pragma unroll
          for (int j=0;j<4;j++){
            int gr = wr*64 + mi*16 + (l>>4)*4 + j;
            int gc = nt*64 + wc*16 + (l&15);
            float v = acc[mi][j], u2 = acc2[mi][j];
            float sg = v*frcp(1.f + fexp2(-v*L2E));
            Sc[(size_t)(mt*256+gr)*2752 + gc] = f2h(sg*u2);
          }
      }
      sig_wait(&FLAGS[16+c], tid);

      // ---- stage G2: out = x2 + S@Wd^T, 256x64 tiles, 128 tasks ----
      for (int task = wid; task < 128; task += 248){
        int mt = task>>4, nt = task&15;
        const unsigned short* A = Sc  + (size_t)mt*256*2752;
        const unsigned short* B = WDT + (size_t)nt*64*2752;
        f32x4 acc[4];
        f32x4 z = {0.f,0.f,0.f,0.f};
        #pragma unroll
        for (int mi=0;mi<4;mi++) acc[mi]=z;
        for (int kt = 0; kt < 2752; kt += 32){
          GLOAD16(A + (size_t)rA*2752 + kt + uA*8, smA + w*1024);
          if (w < 4) GLOAD16(B + (size_t)rB*2752 + kt + uB*8, smB + w4*1024);
          __syncthreads();
          short8 af[4], bf;
          #pragma unroll
          for (int mi=0;mi<4;mi++) af[mi] = *(const short8*)(smA + swz(wr*64 + mi*16 + (l&15), l>>4));
          bf = *(const short8*)(smB + swz(wc*16 + (l&15), l>>4));
          #pragma unroll
          for (int mi=0;mi<4;mi++)
            acc[mi] = __builtin_amdgcn_mfma_f32_16x16x32_f16(as_f16x8(af[mi]), as_f16x8(bf), acc[mi], 0,0,0);
          __syncthreads();
        }
        #pragma unroll
        for (int mi=0;mi<4;mi++)
          #pragma unroll
          for (int j=0;j<4;j++){
            int gr = wr*64 + mi*16 + (l>>4)*4 + j;
            int gc = nt*64 + wc*16 + (l&15);
            size_t idx = (size_t)(mt*2048 + c*256 + gr)*1024 + gc;
            X2OUT[idx] = X2OUT[idx] + acc[mi][j];
          }
      }
      sig_wait(&FLAGS[24+c], tid);
    }
  }
}

// ---------------- launch ----------------------------------------------------------
extern "C" void kernel_launch(void* const* d_in, const int* in_sizes, int n_in,
                              void* d_out, int out_size, void* d_ws, size_t ws_size,
                              hipStream_t stream){
  (void)in_sizes; (void)n_in; (void)out_size;
  const float* x    = (const float*)d_in[0];
  const float* ln1w = (const float*)d_in[1];
  const float* Wg_  = (const float*)d_in[2];
  const float* Rg_  = (const float*)d_in[3];
  const float* bg_  = (const float*)d_in[4];
  const float* gnw  = (const float*)d_in[5];
  const float* ln2w = (const float*)d_in[6];
  const float* Wgf  = (const float*)d_in[7];
  const float* Wuf  = (const float*)d_in[8];
  const float* Wdf  = (const float*)d_in[9];
  float* out = (float*)d_out;
  char* ws = (char*)d_ws;

  // workspace layout (total 187,858,944 B):
  //   [0..20.1M)   persistent weights; bias region doubles as FLAGS post-gemm0
  //   [20.1M..53.6M)  xn (rms1 out) -> hs (scan out)
  //   [53.6M..187.9M) gx; per-chunk scratch (y2c+Sc) reuses gx chunk c's region
  //   x2 lives in d_out (fully rewritten each launch)
  if (ws_size < 187858944ull) return;
  unsigned short* wbt = (unsigned short*)(ws + 0);
  float*          bias= (float*)        (ws + 2097152);
  int*            flags=(int*)          (ws + 2097152);   // aliases bias (dead post-gemm0)
  signed char*    rq  = (signed char*)  (ws + 2113536);
  float*          sc2 = (float*)        (ws + 3162112);
  unsigned short* wgt = (unsigned short*)(ws + 3178496);
  unsigned short* wut = (unsigned short*)(ws + 8814592);
  unsigned short* wdt = (unsigned short*)(ws + 14450688);
  unsigned short* xn  = (unsigned short*)(ws + 20086784);
  unsigned short* hs  = (unsigned short*)(ws + 20086784);  // aliases xn
  unsigned short* gx  = (unsigned short*)(ws + 53641216);

  prep_wbt<<<4096,256,0,stream>>>(Wg_, bg_, wbt, bias);
  prep_rq <<<4096,256,0,stream>>>(Rg_, rq, sc2);
  transpose_cast<<<dim3(86,32),256,0,stream>>>(Wgf, wgt, 1024, 2752);
  transpose_cast<<<dim3(86,32),256,0,stream>>>(Wuf, wut, 1024, 2752);
  transpose_cast<<<dim3(32,86),256,0,stream>>>(Wdf, wdt, 2752, 1024);

  rmsnorm_k<<<16384,256,0,stream>>>(x, ln1w, xn);
  gemm0_k<<<dim3(8,128,4),256,0,stream>>>(xn, wbt, gx, bias);
  hipMemsetAsync(flags, 0, 128, stream);
  mega_k<<<256,1024,0,stream>>>(gx, rq, sc2, hs, flags, x, gnw, ln2w,
                                wgt, wut, wdt, (char*)gx, out);
}

// Round 15
// 2735.524 us; speedup vs baseline: 2.2996x; 1.9383x over previous
//
#include <hip/hip_runtime.h>
#include <hip/hip_bf16.h>

#define DEV __device__ __forceinline__

typedef __attribute__((ext_vector_type(4))) float f32x4;
typedef __attribute__((ext_vector_type(8))) short short8;
typedef __attribute__((ext_vector_type(8))) _Float16 f16x8;
typedef __attribute__((ext_vector_type(4))) int i32x4;
typedef __attribute__((ext_vector_type(4))) unsigned short u16x4;

typedef __attribute__((address_space(3))) void lds_void;
typedef const __attribute__((address_space(1))) void g_void;
#define GLOAD16(g, l) __builtin_amdgcn_global_load_lds((g_void*)(g), (lds_void*)(l), 16, 0, 0)

DEV unsigned short f2h(float f){ union{_Float16 h; unsigned short u;} c; c.h = (_Float16)f; return c.u; }
DEV float h2f(unsigned short u){ union{unsigned short u; _Float16 h;} c; c.u = u; return (float)c.h; }
DEV f16x8 as_f16x8(short8 s){ union{short8 s; f16x8 h;} c; c.s = s; return c.h; }
DEV float fexp2(float x){
#if __has_builtin(__builtin_amdgcn_exp2f)
  return __builtin_amdgcn_exp2f(x);
#else
  return exp2f(x);
#endif
}
DEV float frcp(float x){
#if __has_builtin(__builtin_amdgcn_rcpf)
  return __builtin_amdgcn_rcpf(x);
#else
  return 1.f/x;
#endif
}
DEV float wsum(float v){
  #pragma unroll
  for(int o=32;o;o>>=1) v += __shfl_xor(v,o,64);
  return v;
}
DEV float wmax_(float v){
  #pragma unroll
  for(int o=32;o;o>>=1) v = fmaxf(v,__shfl_xor(v,o,64));
  return v;
}
// XOR swizzle for [rows][32 fp16] LDS tiles, row stride 64B, 16B units.
DEV int swz(int row, int unit){ return row*64 + ((unit ^ ((row>>1)&3))<<4); }

// ---------------- prep: W_gates fp32 -> fp16 bt-layout [n][g*256+k][h] -----------
__global__ __launch_bounds__(256) void prep_wbt(const float* __restrict__ W,
    const float* __restrict__ BG, unsigned short* __restrict__ WBT, float* __restrict__ BIAS){
  int bid = blockIdx.x;                 // (g,n,k) row-major, 4096 blocks
  int g = bid>>10, n = (bid>>8)&3, k = bid&255;
  int C = g*256 + k;
  int h = threadIdx.x;
  WBT[((size_t)n*1024 + C)*256 + h] = f2h(W[(size_t)bid*256 + h]);
  if (h==0) BIAS[n*1024 + C] = BG[(g*4+n)*256 + k];
}

// ---------------- prep: R_gates fp32 -> int8 fragment layout + per-col scales ----
__global__ __launch_bounds__(256) void prep_rq(const float* __restrict__ R,
    signed char* __restrict__ RQ, float* __restrict__ SC){
  int bid = blockIdx.x;                 // (g,n,k)
  int g = bid>>10, n = (bid>>8)&3, k = bid&255;
  int h = threadIdx.x;
  float v = R[(size_t)bid*256 + h];
  float a = fabsf(v);
  float m = wmax_(a);
  __shared__ float red[4];
  int wv = threadIdx.x>>6, l = threadIdx.x&63;
  if (!l) red[wv] = m;
  __syncthreads();
  m = fmaxf(fmaxf(red[0],red[1]), fmaxf(red[2],red[3]));
  float s = fmaxf(m, 1e-20f) * (1.f/127.f);
  int q = (int)rintf(v/s);
  q = q > 127 ? 127 : (q < -127 ? -127 : q);
  int w  = k>>5, kblk = (k>>4)&1, f = (kblk<<2)|g, kf = h>>6;
  int ln = (k&15) | (((h>>4)&3)<<4);
  int j  = h&15;
  RQ[ (((size_t)(n*8+w)*32 + (f*4+kf))*64 + ln)*16 + j ] = (signed char)q;
  if (h==0) SC[n*1024 + g*256 + k] = s * (1.f/127.f);
}

// ---------------- prep: transpose fp32 [K][N] -> fp16 [N][K] ----------------------
__global__ __launch_bounds__(256) void transpose_cast(const float* __restrict__ IN,
    unsigned short* __restrict__ OUT, int K, int N){
  __shared__ float tile[32][33];
  int n0 = blockIdx.x*32, k0 = blockIdx.y*32;
  int c = threadIdx.x&31, r4 = threadIdx.x>>5;
  #pragma unroll
  for (int rr = r4; rr < 32; rr += 8) tile[rr][c] = IN[(size_t)(k0+rr)*N + n0 + c];
  __syncthreads();
  #pragma unroll
  for (int rr = r4; rr < 32; rr += 8) OUT[(size_t)(n0+rr)*K + k0 + c] = f2h(tile[c][rr]);
}

// ---------------- rmsnorm fp32 -> fp16 (rms1) -------------------------------------
__global__ __launch_bounds__(256) void rmsnorm_k(const float* __restrict__ X,
    const float* __restrict__ W, unsigned short* __restrict__ O){
  size_t row = blockIdx.x;
  const f32x4* xp = (const f32x4*)(X + row*1024);
  f32x4 v = xp[threadIdx.x];
  float s = v[0]*v[0]+v[1]*v[1]+v[2]*v[2]+v[3]*v[3];
  s = wsum(s);
  __shared__ float red[4];
  int wv = threadIdx.x>>6, l = threadIdx.x&63;
  if (!l) red[wv] = s;
  __syncthreads();
  float tot = red[0]+red[1]+red[2]+red[3];
  float rs = rsqrtf(tot*(1.f/1024.f) + 1e-6f);
  int c = threadIdx.x*4;
  u16x4 o;
  #pragma unroll
  for (int j=0;j<4;j++) o[j] = f2h(v[j]*rs*W[c+j]);
  *(u16x4*)(O + row*1024 + c) = o;
}

// ---------------- gate GEMM, 128x128 tile -----------------------------------------
__global__ __launch_bounds__(256,2) void gemm0_k(
    const unsigned short* __restrict__ A, const unsigned short* __restrict__ B1,
    unsigned short* __restrict__ OB, const float* __restrict__ BIAS){
  __shared__ __align__(16) char smA[128*64];
  __shared__ __align__(16) char smB[128*64];
  int tid = threadIdx.x, w = tid>>6, l = tid&63;
  int n0 = blockIdx.x*128, m0 = blockIdx.y*128, head = blockIdx.z;
  A += (size_t)head*256; B1 += (size_t)head*1024*256;
  f32x4 acc[4][4];
  f32x4 z = {0.f,0.f,0.f,0.f};
  #pragma unroll
  for (int mi=0;mi<4;mi++)
    #pragma unroll
    for (int ni=0;ni<4;ni++) acc[mi][ni]=z;
  int wr = w>>1, wc = w&1;
  for (int kt = 0; kt < 256; kt += 32){
    #pragma unroll
    for (int c2=0;c2<2;c2++){
      int p = c2*256 + tid;
      int rr = p>>2, u = (p&3) ^ ((rr>>1)&3);
      int ldsb = (c2*256 + w*64)*16;
      GLOAD16(A  + (size_t)(m0+rr)*1024 + kt + u*8, smA + ldsb);
      GLOAD16(B1 + (size_t)(n0+rr)*256  + kt + u*8, smB + ldsb);
    }
    __syncthreads();
    short8 af[4], bf[4];
    #pragma unroll
    for (int mi=0;mi<4;mi++) af[mi] = *(const short8*)(smA + swz(wr*64 + mi*16 + (l&15), l>>4));
    #pragma unroll
    for (int ni=0;ni<4;ni++) bf[ni] = *(const short8*)(smB + swz(wc*64 + ni*16 + (l&15), l>>4));
    #pragma unroll
    for (int mi=0;mi<4;mi++)
      #pragma unroll
      for (int ni=0;ni<4;ni++)
        acc[mi][ni] = __builtin_amdgcn_mfma_f32_16x16x32_f16(as_f16x8(af[mi]), as_f16x8(bf[ni]), acc[mi][ni], 0,0,0);
    __syncthreads();
  }
  int rbase = m0 + wr*64, cbase = n0 + wc*64;
  #pragma unroll
  for (int mi=0;mi<4;mi++)
    #pragma unroll
    for (int ni=0;ni<4;ni++)
      #pragma unroll
      for (int j=0;j<4;j++){
        int gr = rbase + mi*16 + (l>>4)*4 + j;
        int gc = cbase + ni*16 + (l&15);
        int t = gr & 2047, b = gr >> 11;
        int g = gc >> 8, k = gc & 255;
        float fac = (g==2) ? 2.8853900817779268f : 1.4426950408889634f;
        OB[ (((size_t)t*4 + head)*256 + k)*32 + (b>>1)*8 + (b&1)*4 + g ]
          = f2h((acc[mi][ni][j] + BIAS[head*1024 + gc]) * fac);
      }
}

// ================== MEGA kernel: scan (WG 0-7) + downstream workers (WG 8-255) ====
// Spin loops poll with RELAXED atomics at s_sleep(127) cadence (~3.4us): round
// 12-14's s_sleep(2) polling from ~200 idle WGs was ~4.6G device-scope loads/s
// on one cache line -- a fabric storm that stretched everything ~3x.
#define SCAN_STEP(HR, HW, GXV, TT) do{                                          \
    i32x4 af[4];                                                                \
    _Pragma("unroll")                                                           \
    for (int kf=0;kf<4;kf++) af[kf] = *(const i32x4*)(&HR[ra + kf*64]);         \
    i32x4 acc[4];                                                               \
    _Pragma("unroll")                                                           \
    for (int g=0; g<4; g++){                                                    \
      i32x4 a = {0,0,0,0};                                                      \
      _Pragma("unroll")                                                         \
      for (int kf=0; kf<4; kf++)                                                \
        a = __builtin_amdgcn_mfma_i32_16x16x64_i8(af[kf], wf[g][kf], a, 0,0,0); \
      acc[g] = a;                                                               \
    }                                                                           \
    float ip2 = fmaf(sch[0],(float)acc[0][0], fmaf(scl[0],(float)acc[0][1], h2f(GXV[0]))); \
    float fpv = fmaf(sch[1],(float)acc[1][0], fmaf(scl[1],(float)acc[1][1], h2f(GXV[1]))) + ms; \
    float zp2 = fmaf(sch[2],(float)acc[2][0], fmaf(scl[2],(float)acc[2][1], h2f(GXV[2]))); \
    float op2 = fmaf(sch[3],(float)acc[3][0], fmaf(scl[3],(float)acc[3][1], h2f(GXV[3]))); \
    float mn = fmaxf(fpv, ip2);                                                 \
    float ig = fexp2(ip2 - mn);                                                 \
    float fg = fexp2(fpv - mn);                                                 \
    float e2 = fexp2(zp2);                                                      \
    float tz = fmaf(-2.f, frcp(e2 + 1.f), 1.f);                                 \
    float eo = fexp2(-op2);                                                     \
    float c  = fmaf(ig, tz, fg*cs);                                             \
    float nn = fmaf(fg, ns_, ig);                                               \
    float h  = c * frcp((1.f + eo)*nn);                                         \
    cs=c; ns_=nn; ms=mn;                                                        \
    float h127 = h*127.f;                                                       \
    float hiq = rintf(h127);                                                    \
    float loq = rintf((h127 - hiq)*127.f);                                      \
    HW[r_hi] = (signed char)(int)hiq;                                           \
    HW[r_lo] = (signed char)(int)loq;                                           \
    HS[(size_t)(TT)*8192 + hoff] = f2h(h);                                      \
  }while(0)

DEV void slow_spin(int* f, int n){
  while (__hip_atomic_load(f, __ATOMIC_RELAXED, __HIP_MEMORY_SCOPE_AGENT) < n)
    __builtin_amdgcn_s_sleep(127);
  (void)__hip_atomic_load(f, __ATOMIC_ACQUIRE, __HIP_MEMORY_SCOPE_AGENT);
}

DEV void sig_wait(int* f, int tid){
  asm volatile("s_waitcnt vmcnt(0) lgkmcnt(0)" ::: "memory");
  __syncthreads();
  if (tid==0){
    __hip_atomic_fetch_add(f, 1, __ATOMIC_RELEASE, __HIP_MEMORY_SCOPE_AGENT);
    slow_spin(f, 248);
  }
  __syncthreads();
}

__global__ __launch_bounds__(1024,4) void mega_k(
    const unsigned short* GX, const signed char* RQ, const float* SC,
    unsigned short* HS, int* FLAGS,
    const float* X, const float* GNW, const float* LN2W,
    const unsigned short* WGT, const unsigned short* WUT, const unsigned short* WDT,
    char* CHUNK0, float* X2OUT){
  __shared__ __align__(16) char smem[86016];   // 1 WG/CU
  int tid = threadIdx.x;
  const float L2E = 1.44269504f;

  if (blockIdx.x < 8){
    // ---------------- scan path (unchanged core) ----------------
    int bid = blockIdx.x;
    int n = bid >> 1, bg = bid & 1;
    int w = tid>>6, l = tid&63;
    signed char* hlA = (signed char*)smem;
    signed char* hlB = (signed char*)(smem + 4352);
    for (int i = tid; i < 8704; i += 1024) smem[i] = 0;

    int l15 = l & 15, q = l >> 4;
    i32x4 wf[4][4];
    {
      const i32x4* rp = (const i32x4*)RQ + (size_t)(n*8 + (w>>1))*32*64;
      #pragma unroll
      for (int g=0; g<4; g++){
        int f = ((w&1)<<2) | g;
        #pragma unroll
        for (int kf=0; kf<4; kf++)
          wf[g][kf] = rp[(f*4+kf)*64 + l];
      }
    }
    float sch[4], scl[4];
    {
      const float facs[4] = {1.4426950408889634f, 1.4426950408889634f,
                             2.8853900817779268f, 1.4426950408889634f};
      #pragma unroll
      for (int g=0; g<4; g++){
        float s = SC[n*1024 + g*256 + w*16 + l15] * facs[g];
        sch[g] = s; scl[g] = s*(1.f/127.f);
      }
    }
    float cs = 0.f, ns_ = 0.f, ms = 0.f;
    int goff = (n*256 + w*16 + l15)*32 + (bg*2 + (q>>1))*8 + (q&1)*4;
    int hoff = (n*8 + bg*4 + q)*256 + w*16 + l15;
    int ra   = l15*272 + q*16;
    int r_hi = (4*q + 0)*272 + w*16 + l15;
    int r_lo = r_hi + 272;

    u16x4 gxr = *(const u16x4*)(GX + goff);
    __syncthreads();

    for (int t = 0; t < 2048; t += 2){
      u16x4 gx1 = *(const u16x4*)(GX + (size_t)(t+1)*32768 + goff);
      SCAN_STEP(hlA, hlB, gxr, t);
      asm volatile("s_waitcnt lgkmcnt(0)" ::: "memory");
      __builtin_amdgcn_s_barrier();
      __builtin_amdgcn_sched_barrier(0);
      int tt2 = (t+2 < 2048) ? (t+2) : 2047;
      gxr = *(const u16x4*)(GX + (size_t)tt2*32768 + goff);
      SCAN_STEP(hlB, hlA, gx1, t+1);
      asm volatile("s_waitcnt lgkmcnt(0)" ::: "memory");
      __builtin_amdgcn_s_barrier();
      __builtin_amdgcn_sched_barrier(0);
      if (((t+2) & 255) == 0){
        asm volatile("s_waitcnt vmcnt(0)" ::: "memory");
        __builtin_amdgcn_s_barrier();
        if (tid == 0)
          __hip_atomic_fetch_add(&FLAGS[(t+1)>>8], 1, __ATOMIC_RELEASE, __HIP_MEMORY_SCOPE_AGENT);
      }
    }
  } else {
    // ---------------- worker path ----------------
    int wid = blockIdx.x - 8;               // 0..247
    int w = tid>>6, l = tid&63;
    int wr = w>>2, wc = w&3;                 // 4x4 wave grid, wave tile 64x16
    char* smA  = smem;                       // 256x32 fp16 = 16KB
    char* smB  = smem + 16384;               // 64x32 fp16 = 4KB
    char* smB2 = smem + 20480;               // 64x32 fp16 = 4KB
    float* red = (float*)(smem + 32768);

    int pA = w*64 + l, rA = pA>>2, uA = (pA&3)^((rA>>1)&3);
    int w4 = w & 3;
    int pB = w4*64 + l, rB = pB>>2, uB = (pB&3)^((rB>>1)&3);

    for (int c = 0; c < 8; ++c){
      char* cb = CHUNK0 + (size_t)c*16777216;
      unsigned short* y2c = (unsigned short*)cb;
      unsigned short* Sc  = (unsigned short*)(cb + 4194304);

      if (tid==0) slow_spin(&FLAGS[c], 8);
      __syncthreads();

      // ---- stage N: x2 = x + LN(hs)*gnw ; y2c = rmsnorm(x2)*ln2w ----
      {
        int hn = tid>>8, hk = tid&255;
        for (int r = wid; r < 2048; r += 248){
          int b = r>>8, tl = r&255, t = c*256 + tl;
          float v = h2f(HS[(((size_t)t*4+hn)*8+b)*256 + hk]);
          float s1 = wsum(v), s2 = wsum(v*v);
          if (!(tid&63)){ red[tid>>6] = s1; red[16+(tid>>6)] = s2; }
          __syncthreads();
          float sum = 0.f, sq = 0.f;
          #pragma unroll
          for (int i=0;i<4;i++){ sum += red[hn*4+i]; sq += red[16+hn*4+i]; }
          float mu = sum*(1.f/256.f);
          float var = sq*(1.f/256.f) - mu*mu;
          float rs = rsqrtf(var + 1e-5f);
          size_t xi = (size_t)(b*2048+t)*1024 + tid;
          float x2v = X[xi] + (v-mu)*rs*GNW[tid];
          X2OUT[xi] = x2v;
          float qq = wsum(x2v*x2v);
          if (!(tid&63)) red[32+(tid>>6)] = qq;
          __syncthreads();
          float tot = 0.f;
          #pragma unroll
          for (int i=0;i<16;i++) tot += red[32+i];
          float rs2 = rsqrtf(tot*(1.f/1024.f) + 1e-6f);
          y2c[(size_t)r*1024 + tid] = f2h(x2v*rs2*LN2W[tid]);
          __syncthreads();
        }
      }
      sig_wait(&FLAGS[8+c], tid);

      // ---- stage G1: S = silu(y2c@Wg^T) * (y2c@Wu^T), 256x64 tiles, 344 tasks ----
      for (int task = wid; task < 344; task += 248){
        int mt = task/43, nt = task - mt*43;
        const unsigned short* A  = y2c + (size_t)mt*256*1024;
        const unsigned short* B1 = WGT + (size_t)nt*64*1024;
        const unsigned short* B2 = WUT + (size_t)nt*64*1024;
        f32x4 acc[4], acc2[4];
        f32x4 z = {0.f,0.f,0.f,0.f};
        #pragma unroll
        for (int mi=0;mi<4;mi++){ acc[mi]=z; acc2[mi]=z; }
        for (int kt = 0; kt < 1024; kt += 32){
          GLOAD16(A + (size_t)rA*1024 + kt + uA*8, smA + w*1024);
          if (w < 4)      GLOAD16(B1 + (size_t)rB*1024 + kt + uB*8, smB  + w4*1024);
          else if (w < 8) GLOAD16(B2 + (size_t)rB*1024 + kt + uB*8, smB2 + w4*1024);
          __syncthreads();
          short8 af[4], bf, bg;
          #pragma unroll
          for (int mi=0;mi<4;mi++) af[mi] = *(const short8*)(smA + swz(wr*64 + mi*16 + (l&15), l>>4));
          bf = *(const short8*)(smB  + swz(wc*16 + (l&15), l>>4));
          bg = *(const short8*)(smB2 + swz(wc*16 + (l&15), l>>4));
          #pragma unroll
          for (int mi=0;mi<4;mi++){
            acc[mi]  = __builtin_amdgcn_mfma_f32_16x16x32_f16(as_f16x8(af[mi]), as_f16x8(bf), acc[mi], 0,0,0);
            acc2[mi] = __builtin_amdgcn_mfma_f32_16x16x32_f16(as_f16x8(af[mi]), as_f16x8(bg), acc2[mi], 0,0,0);
          }
          __syncthreads();
        }
        #pragma unroll
        for (int mi=0;mi<4;mi++)
          #pragma unroll
          for (int j=0;j<4;j++){
            int gr = wr*64 + mi*16 + (l>>4)*4 + j;
            int gc = nt*64 + wc*16 + (l&15);
            float v = acc[mi][j], u2 = acc2[mi][j];
            float sg = v*frcp(1.f + fexp2(-v*L2E));
            Sc[(size_t)(mt*256+gr)*2752 + gc] = f2h(sg*u2);
          }
      }
      sig_wait(&FLAGS[16+c], tid);

      // ---- stage G2: out = x2 + S@Wd^T, 256x64 tiles, 128 tasks ----
      for (int task = wid; task < 128; task += 248){
        int mt = task>>4, nt = task&15;
        const unsigned short* A = Sc  + (size_t)mt*256*2752;
        const unsigned short* B = WDT + (size_t)nt*64*2752;
        f32x4 acc[4];
        f32x4 z = {0.f,0.f,0.f,0.f};
        #pragma unroll
        for (int mi=0;mi<4;mi++) acc[mi]=z;
        for (int kt = 0; kt < 2752; kt += 32){
          GLOAD16(A + (size_t)rA*2752 + kt + uA*8, smA + w*1024);
          if (w < 4) GLOAD16(B + (size_t)rB*2752 + kt + uB*8, smB + w4*1024);
          __syncthreads();
          short8 af[4], bf;
          #pragma unroll
          for (int mi=0;mi<4;mi++) af[mi] = *(const short8*)(smA + swz(wr*64 + mi*16 + (l&15), l>>4));
          bf = *(const short8*)(smB + swz(wc*16 + (l&15), l>>4));
          #pragma unroll
          for (int mi=0;mi<4;mi++)
            acc[mi] = __builtin_amdgcn_mfma_f32_16x16x32_f16(as_f16x8(af[mi]), as_f16x8(bf), acc[mi], 0,0,0);
          __syncthreads();
        }
        #pragma unroll
        for (int mi=0;mi<4;mi++)
          #pragma unroll
          for (int j=0;j<4;j++){
            int gr = wr*64 + mi*16 + (l>>4)*4 + j;
            int gc = nt*64 + wc*16 + (l&15);
            size_t idx = (size_t)(mt*2048 + c*256 + gr)*1024 + gc;
            X2OUT[idx] = X2OUT[idx] + acc[mi][j];
          }
      }
      sig_wait(&FLAGS[24+c], tid);
    }
  }
}

// ---------------- launch ----------------------------------------------------------
extern "C" void kernel_launch(void* const* d_in, const int* in_sizes, int n_in,
                              void* d_out, int out_size, void* d_ws, size_t ws_size,
                              hipStream_t stream){
  (void)in_sizes; (void)n_in; (void)out_size;
  const float* x    = (const float*)d_in[0];
  const float* ln1w = (const float*)d_in[1];
  const float* Wg_  = (const float*)d_in[2];
  const float* Rg_  = (const float*)d_in[3];
  const float* bg_  = (const float*)d_in[4];
  const float* gnw  = (const float*)d_in[5];
  const float* ln2w = (const float*)d_in[6];
  const float* Wgf  = (const float*)d_in[7];
  const float* Wuf  = (const float*)d_in[8];
  const float* Wdf  = (const float*)d_in[9];
  float* out = (float*)d_out;
  char* ws = (char*)d_ws;

  // workspace layout (total 187,858,944 B):
  //   [0..20.1M)   persistent weights; bias region doubles as FLAGS post-gemm0
  //   [20.1M..53.6M)  xn (rms1 out) -> hs (scan out)
  //   [53.6M..187.9M) gx; per-chunk scratch (y2c+Sc) reuses gx chunk c's region
  //   x2 lives in d_out (fully rewritten each launch)
  if (ws_size < 187858944ull) return;
  unsigned short* wbt = (unsigned short*)(ws + 0);
  float*          bias= (float*)        (ws + 2097152);
  int*            flags=(int*)          (ws + 2097152);   // aliases bias (dead post-gemm0)
  signed char*    rq  = (signed char*)  (ws + 2113536);
  float*          sc2 = (float*)        (ws + 3162112);
  unsigned short* wgt = (unsigned short*)(ws + 3178496);
  unsigned short* wut = (unsigned short*)(ws + 8814592);
  unsigned short* wdt = (unsigned short*)(ws + 14450688);
  unsigned short* xn  = (unsigned short*)(ws + 20086784);
  unsigned short* hs  = (unsigned short*)(ws + 20086784);  // aliases xn
  unsigned short* gx  = (unsigned short*)(ws + 53641216);

  prep_wbt<<<4096,256,0,stream>>>(Wg_, bg_, wbt, bias);
  prep_rq <<<4096,256,0,stream>>>(Rg_, rq, sc2);
  transpose_cast<<<dim3(86,32),256,0,stream>>>(Wgf, wgt, 1024, 2752);
  transpose_cast<<<dim3(86,32),256,0,stream>>>(Wuf, wut, 1024, 2752);
  transpose_cast<<<dim3(32,86),256,0,stream>>>(Wdf, wdt, 2752, 1024);

  rmsnorm_k<<<16384,256,0,stream>>>(x, ln1w, xn);
  gemm0_k<<<dim3(8,128,4),256,0,stream>>>(xn, wbt, gx, bias);
  hipMemsetAsync(flags, 0, 128, stream);
  mega_k<<<256,1024,0,stream>>>(gx, rq, sc2, hs, flags, x, gnw, ln2w,
                                wgt, wut, wdt, (char*)gx, out);
}

// Round 16
// 2538.227 us; speedup vs baseline: 2.4784x; 1.0777x over previous
//
#include <hip/hip_runtime.h>
#include <hip/hip_bf16.h>

#define DEV __device__ __forceinline__

typedef __attribute__((ext_vector_type(4))) float f32x4;
typedef __attribute__((ext_vector_type(8))) short short8;
typedef __attribute__((ext_vector_type(8))) _Float16 f16x8;
typedef __attribute__((ext_vector_type(4))) int i32x4;
typedef __attribute__((ext_vector_type(4))) unsigned short u16x4;
typedef __attribute__((ext_vector_type(8))) unsigned short u16x8;

typedef __attribute__((address_space(3))) void lds_void;
typedef const __attribute__((address_space(1))) void g_void;
#define GLOAD16(g, l) __builtin_amdgcn_global_load_lds((g_void*)(g), (lds_void*)(l), 16, 0, 0)

DEV unsigned short f2h(float f){ union{_Float16 h; unsigned short u;} c; c.h = (_Float16)f; return c.u; }
DEV float h2f(unsigned short u){ union{unsigned short u; _Float16 h;} c; c.u = u; return (float)c.h; }
DEV f16x8 as_f16x8(short8 s){ union{short8 s; f16x8 h;} c; c.s = s; return c.h; }
DEV float fexp2(float x){
#if __has_builtin(__builtin_amdgcn_exp2f)
  return __builtin_amdgcn_exp2f(x);
#else
  return exp2f(x);
#endif
}
DEV float frcp(float x){
#if __has_builtin(__builtin_amdgcn_rcpf)
  return __builtin_amdgcn_rcpf(x);
#else
  return 1.f/x;
#endif
}
DEV float wsum(float v){
  #pragma unroll
  for(int o=32;o;o>>=1) v += __shfl_xor(v,o,64);
  return v;
}
DEV float wmax_(float v){
  #pragma unroll
  for(int o=32;o;o>>=1) v = fmaxf(v,__shfl_xor(v,o,64));
  return v;
}
// XOR swizzle for [rows][32 fp16] LDS tiles, row stride 64B, 16B units.
DEV int swz(int row, int unit){ return row*64 + ((unit ^ ((row>>1)&3))<<4); }

// ---------------- prep: W_gates fp32 -> fp16 bt-layout [n][C'=(k<<2)|g][h] -------
__global__ __launch_bounds__(256) void prep_wbt(const float* __restrict__ W,
    const float* __restrict__ BG, unsigned short* __restrict__ WBT, float* __restrict__ BIAS){
  int bid = blockIdx.x;                 // (g,n,k) row-major, 4096 blocks
  int g = bid>>10, n = (bid>>8)&3, k = bid&255;
  int C = (k<<2) | g;                   // gx-granule-aligned column code
  int h = threadIdx.x;
  WBT[((size_t)n*1024 + C)*256 + h] = f2h(W[(size_t)bid*256 + h]);
  if (h==0) BIAS[n*1024 + C] = BG[(g*4+n)*256 + k];
}

// ---------------- prep: R_gates fp32 -> int8 fragment layout + per-col scales ----
__global__ __launch_bounds__(256) void prep_rq(const float* __restrict__ R,
    signed char* __restrict__ RQ, float* __restrict__ SC){
  int bid = blockIdx.x;                 // (g,n,k)
  int g = bid>>10, n = (bid>>8)&3, k = bid&255;
  int h = threadIdx.x;
  float v = R[(size_t)bid*256 + h];
  float a = fabsf(v);
  float m = wmax_(a);
  __shared__ float red[4];
  int wv = threadIdx.x>>6, l = threadIdx.x&63;
  if (!l) red[wv] = m;
  __syncthreads();
  m = fmaxf(fmaxf(red[0],red[1]), fmaxf(red[2],red[3]));
  float s = fmaxf(m, 1e-20f) * (1.f/127.f);
  int q = (int)rintf(v/s);
  q = q > 127 ? 127 : (q < -127 ? -127 : q);
  int w  = k>>5, kblk = (k>>4)&1, f = (kblk<<2)|g, kf = h>>6;
  int ln = (k&15) | (((h>>4)&3)<<4);
  int j  = h&15;
  RQ[ (((size_t)(n*8+w)*32 + (f*4+kf))*64 + ln)*16 + j ] = (signed char)q;
  if (h==0) SC[n*1024 + g*256 + k] = s * (1.f/127.f);
}

// ---------------- prep: transpose fp32 [K][N] -> fp16 [N][K] ----------------------
__global__ __launch_bounds__(256) void transpose_cast(const float* __restrict__ IN,
    unsigned short* __restrict__ OUT, int K, int N){
  __shared__ float tile[32][33];
  int n0 = blockIdx.x*32, k0 = blockIdx.y*32;
  int c = threadIdx.x&31, r4 = threadIdx.x>>5;
  #pragma unroll
  for (int rr = r4; rr < 32; rr += 8) tile[rr][c] = IN[(size_t)(k0+rr)*N + n0 + c];
  __syncthreads();
  #pragma unroll
  for (int rr = r4; rr < 32; rr += 8) OUT[(size_t)(n0+rr)*K + k0 + c] = f2h(tile[c][rr]);
}

// ---------------- rmsnorm fp32 -> fp16, output row permuted to [t][b] -------------
__global__ __launch_bounds__(256) void rmsnorm_k(const float* __restrict__ X,
    const float* __restrict__ W, unsigned short* __restrict__ O){
  size_t row = blockIdx.x;
  const f32x4* xp = (const f32x4*)(X + row*1024);
  f32x4 v = xp[threadIdx.x];
  float s = v[0]*v[0]+v[1]*v[1]+v[2]*v[2]+v[3]*v[3];
  s = wsum(s);
  __shared__ float red[4];
  int wv = threadIdx.x>>6, l = threadIdx.x&63;
  if (!l) red[wv] = s;
  __syncthreads();
  float tot = red[0]+red[1]+red[2]+red[3];
  float rs = rsqrtf(tot*(1.f/1024.f) + 1e-6f);
  int c = threadIdx.x*4;
  u16x4 o;
  #pragma unroll
  for (int j=0;j<4;j++) o[j] = f2h(v[j]*rs*W[c+j]);
  size_t orow = (row & 2047)*8 + (row >> 11);   // xn' row = t*8 + b
  *(u16x4*)(O + orow*1024 + c) = o;
}

// ---------------- gate GEMM, 128x128 tile, LDS-staged coalesced gx write ----------
// A = xn' [t*8+b][1024]; B = wbt [C'=(k<<2)|g][256]. Tile = {16t x 8b} x {32k x 4g}
// = 16 full 2KB gx rows -> coalesced streaming store (was 32x write-amplified).
__global__ __launch_bounds__(256,2) void gemm0_k(
    const unsigned short* __restrict__ A, const unsigned short* __restrict__ B1,
    unsigned short* __restrict__ OB, const float* __restrict__ BIAS){
  __shared__ __align__(16) char smem[32768];
  char* smA = smem;
  char* smB = smem + 8192;
  int tid = threadIdx.x, w = tid>>6, l = tid&63;
  int n0 = blockIdx.x*128, m0 = blockIdx.y*128, head = blockIdx.z;
  A += (size_t)head*256; B1 += (size_t)head*1024*256;
  f32x4 acc[4][4];
  f32x4 z = {0.f,0.f,0.f,0.f};
  #pragma unroll
  for (int mi=0;mi<4;mi++)
    #pragma unroll
    for (int ni=0;ni<4;ni++) acc[mi][ni]=z;
  int wr = w>>1, wc = w&1;
  for (int kt = 0; kt < 256; kt += 32){
    #pragma unroll
    for (int c2=0;c2<2;c2++){
      int p = c2*256 + tid;
      int rr = p>>2, u = (p&3) ^ ((rr>>1)&3);
      int ldsb = (c2*256 + w*64)*16;
      GLOAD16(A  + (size_t)(m0+rr)*1024 + kt + u*8, smA + ldsb);
      GLOAD16(B1 + (size_t)(n0+rr)*256  + kt + u*8, smB + ldsb);
    }
    __syncthreads();
    short8 af[4], bf[4];
    #pragma unroll
    for (int mi=0;mi<4;mi++) af[mi] = *(const short8*)(smA + swz(wr*64 + mi*16 + (l&15), l>>4));
    #pragma unroll
    for (int ni=0;ni<4;ni++) bf[ni] = *(const short8*)(smB + swz(wc*64 + ni*16 + (l&15), l>>4));
    #pragma unroll
    for (int mi=0;mi<4;mi++)
      #pragma unroll
      for (int ni=0;ni<4;ni++)
        acc[mi][ni] = __builtin_amdgcn_mfma_f32_16x16x32_f16(as_f16x8(af[mi]), as_f16x8(bf[ni]), acc[mi][ni], 0,0,0);
    __syncthreads();
  }
  // stage tile to LDS in gx granule order: [t_loc 16][k_loc 32][pair 4][db 2][g 4]
  unsigned short* gt = (unsigned short*)smem;
  #pragma unroll
  for (int mi=0;mi<4;mi++)
    #pragma unroll
    for (int ni=0;ni<4;ni++)
      #pragma unroll
      for (int j=0;j<4;j++){
        int rr = wr*64 + mi*16 + (l>>4)*4 + j;   // local xn' row: t_loc = rr>>3, b = rr&7
        int cc = wc*64 + ni*16 + (l&15);         // local C': k_loc = cc>>2, g = cc&3
        int Cp = n0 + cc;
        int g = Cp & 3, b = rr & 7;
        float fac = (g==2) ? 2.8853900817779268f : 1.4426950408889634f;
        gt[ (rr>>3)*1024 + (cc>>2)*32 + (b>>1)*8 + (b&1)*4 + g ]
          = f2h((acc[mi][ni][j] + BIAS[head*1024 + Cp]) * fac);
      }
  __syncthreads();
  // coalesced copy: 16 t-rows x 2KB contiguous each
  int t0 = blockIdx.y*16, k0 = blockIdx.x*32;
  int t_loc = tid>>4, seg = tid&15;              // 16 threads per t, 128B each
  const u16x8* src = (const u16x8*)(gt + t_loc*1024 + seg*64);
  u16x8* dst = (u16x8*)(OB + ((((size_t)(t0+t_loc)*4 + head)*256 + k0)*32) + seg*64);
  #pragma unroll
  for (int i=0;i<8;i++) dst[i] = src[i];
}

// ================== MEGA kernel: scan (WG 0-7) + downstream workers (WG 8-255) ====
// 16 chunks of 128 steps (halves the tail). Relaxed slow polling (round-15 fix).
#define SCAN_STEP(HR, HW, GXV, TT) do{                                          \
    i32x4 af[4];                                                                \
    _Pragma("unroll")                                                           \
    for (int kf=0;kf<4;kf++) af[kf] = *(const i32x4*)(&HR[ra + kf*64]);         \
    i32x4 acc[4];                                                               \
    _Pragma("unroll")                                                           \
    for (int g=0; g<4; g++){                                                    \
      i32x4 a = {0,0,0,0};                                                      \
      _Pragma("unroll")                                                         \
      for (int kf=0; kf<4; kf++)                                                \
        a = __builtin_amdgcn_mfma_i32_16x16x64_i8(af[kf], wf[g][kf], a, 0,0,0); \
      acc[g] = a;                                                               \
    }                                                                           \
    float ip2 = fmaf(sch[0],(float)acc[0][0], fmaf(scl[0],(float)acc[0][1], h2f(GXV[0]))); \
    float fpv = fmaf(sch[1],(float)acc[1][0], fmaf(scl[1],(float)acc[1][1], h2f(GXV[1]))) + ms; \
    float zp2 = fmaf(sch[2],(float)acc[2][0], fmaf(scl[2],(float)acc[2][1], h2f(GXV[2]))); \
    float op2 = fmaf(sch[3],(float)acc[3][0], fmaf(scl[3],(float)acc[3][1], h2f(GXV[3]))); \
    float mn = fmaxf(fpv, ip2);                                                 \
    float ig = fexp2(ip2 - mn);                                                 \
    float fg = fexp2(fpv - mn);                                                 \
    float e2 = fexp2(zp2);                                                      \
    float tz = fmaf(-2.f, frcp(e2 + 1.f), 1.f);                                 \
    float eo = fexp2(-op2);                                                     \
    float c  = fmaf(ig, tz, fg*cs);                                             \
    float nn = fmaf(fg, ns_, ig);                                               \
    float h  = c * frcp((1.f + eo)*nn);                                         \
    cs=c; ns_=nn; ms=mn;                                                        \
    float h127 = h*127.f;                                                       \
    float hiq = rintf(h127);                                                    \
    float loq = rintf((h127 - hiq)*127.f);                                      \
    HW[r_hi] = (signed char)(int)hiq;                                           \
    HW[r_lo] = (signed char)(int)loq;                                           \
    HS[(size_t)(TT)*8192 + hoff] = f2h(h);                                      \
  }while(0)

DEV void slow_spin(int* f, int n){
  while (__hip_atomic_load(f, __ATOMIC_RELAXED, __HIP_MEMORY_SCOPE_AGENT) < n)
    __builtin_amdgcn_s_sleep(127);
  (void)__hip_atomic_load(f, __ATOMIC_ACQUIRE, __HIP_MEMORY_SCOPE_AGENT);
}

DEV void sig_wait(int* f, int tid){
  asm volatile("s_waitcnt vmcnt(0) lgkmcnt(0)" ::: "memory");
  __syncthreads();
  if (tid==0){
    __hip_atomic_fetch_add(f, 1, __ATOMIC_RELEASE, __HIP_MEMORY_SCOPE_AGENT);
    slow_spin(f, 248);
  }
  __syncthreads();
}

__global__ __launch_bounds__(1024,4) void mega_k(
    const unsigned short* GX, const signed char* RQ, const float* SC,
    unsigned short* HS, int* FLAGS,
    const float* X, const float* GNW, const float* LN2W,
    const unsigned short* WGT, const unsigned short* WUT, const unsigned short* WDT,
    char* CHUNK0, float* X2OUT){
  __shared__ __align__(16) char smem[86016];   // 1 WG/CU
  int tid = threadIdx.x;
  const float L2E = 1.44269504f;

  if (blockIdx.x < 8){
    // ---------------- scan path (unchanged core) ----------------
    int bid = blockIdx.x;
    int n = bid >> 1, bg = bid & 1;
    int w = tid>>6, l = tid&63;
    signed char* hlA = (signed char*)smem;
    signed char* hlB = (signed char*)(smem + 4352);
    for (int i = tid; i < 8704; i += 1024) smem[i] = 0;

    int l15 = l & 15, q = l >> 4;
    i32x4 wf[4][4];
    {
      const i32x4* rp = (const i32x4*)RQ + (size_t)(n*8 + (w>>1))*32*64;
      #pragma unroll
      for (int g=0; g<4; g++){
        int f = ((w&1)<<2) | g;
        #pragma unroll
        for (int kf=0; kf<4; kf++)
          wf[g][kf] = rp[(f*4+kf)*64 + l];
      }
    }
    float sch[4], scl[4];
    {
      const float facs[4] = {1.4426950408889634f, 1.4426950408889634f,
                             2.8853900817779268f, 1.4426950408889634f};
      #pragma unroll
      for (int g=0; g<4; g++){
        float s = SC[n*1024 + g*256 + w*16 + l15] * facs[g];
        sch[g] = s; scl[g] = s*(1.f/127.f);
      }
    }
    float cs = 0.f, ns_ = 0.f, ms = 0.f;
    int goff = (n*256 + w*16 + l15)*32 + (bg*2 + (q>>1))*8 + (q&1)*4;
    int hoff = (n*8 + bg*4 + q)*256 + w*16 + l15;
    int ra   = l15*272 + q*16;
    int r_hi = (4*q + 0)*272 + w*16 + l15;
    int r_lo = r_hi + 272;

    u16x4 gxr = *(const u16x4*)(GX + goff);
    __syncthreads();

    for (int t = 0; t < 2048; t += 2){
      u16x4 gx1 = *(const u16x4*)(GX + (size_t)(t+1)*32768 + goff);
      SCAN_STEP(hlA, hlB, gxr, t);
      asm volatile("s_waitcnt lgkmcnt(0)" ::: "memory");
      __builtin_amdgcn_s_barrier();
      __builtin_amdgcn_sched_barrier(0);
      int tt2 = (t+2 < 2048) ? (t+2) : 2047;
      gxr = *(const u16x4*)(GX + (size_t)tt2*32768 + goff);
      SCAN_STEP(hlB, hlA, gx1, t+1);
      asm volatile("s_waitcnt lgkmcnt(0)" ::: "memory");
      __builtin_amdgcn_s_barrier();
      __builtin_amdgcn_sched_barrier(0);
      if (((t+2) & 127) == 0){
        asm volatile("s_waitcnt vmcnt(0)" ::: "memory");
        __builtin_amdgcn_s_barrier();
        if (tid == 0)
          __hip_atomic_fetch_add(&FLAGS[(t+1)>>7], 1, __ATOMIC_RELEASE, __HIP_MEMORY_SCOPE_AGENT);
      }
    }
  } else {
    // ---------------- worker path ----------------
    int wid = blockIdx.x - 8;               // 0..247
    int w = tid>>6, l = tid&63;
    int wr = w>>2, wc = w&3;                 // 4x4 wave grid, wave tile 64x16
    char* smA  = smem;                       // 256x32 fp16 = 16KB
    char* smB  = smem + 16384;               // 64x32 fp16 = 4KB
    char* smB2 = smem + 20480;               // 64x32 fp16 = 4KB
    float* red = (float*)(smem + 32768);

    int pA = w*64 + l, rA = pA>>2, uA = (pA&3)^((rA>>1)&3);
    int w4 = w & 3;
    int pB = w4*64 + l, rB = pB>>2, uB = (pB&3)^((rB>>1)&3);

    for (int c = 0; c < 16; ++c){
      char* cb = CHUNK0 + (size_t)c*8388608;
      unsigned short* y2c = (unsigned short*)cb;
      unsigned short* Sc  = (unsigned short*)(cb + 2097152);

      if (tid==0) slow_spin(&FLAGS[c], 8);
      __syncthreads();

      // ---- stage N: x2 = x + LN(hs)*gnw ; y2c = rmsnorm(x2)*ln2w ----
      {
        int hn = tid>>8, hk = tid&255;
        for (int r = wid; r < 1024; r += 248){
          int b = r>>7, tl = r&127, t = c*128 + tl;
          float v = h2f(HS[(((size_t)t*4+hn)*8+b)*256 + hk]);
          float s1 = wsum(v), s2 = wsum(v*v);
          if (!(tid&63)){ red[tid>>6] = s1; red[16+(tid>>6)] = s2; }
          __syncthreads();
          float sum = 0.f, sq = 0.f;
          #pragma unroll
          for (int i=0;i<4;i++){ sum += red[hn*4+i]; sq += red[16+hn*4+i]; }
          float mu = sum*(1.f/256.f);
          float var = sq*(1.f/256.f) - mu*mu;
          float rs = rsqrtf(var + 1e-5f);
          size_t xi = (size_t)(b*2048+t)*1024 + tid;
          float x2v = X[xi] + (v-mu)*rs*GNW[tid];
          X2OUT[xi] = x2v;
          float qq = wsum(x2v*x2v);
          if (!(tid&63)) red[32+(tid>>6)] = qq;
          __syncthreads();
          float tot = 0.f;
          #pragma unroll
          for (int i=0;i<16;i++) tot += red[32+i];
          float rs2 = rsqrtf(tot*(1.f/1024.f) + 1e-6f);
          y2c[(size_t)r*1024 + tid] = f2h(x2v*rs2*LN2W[tid]);
          __syncthreads();
        }
      }
      sig_wait(&FLAGS[16+c], tid);

      // ---- stage G1: S = silu(y2c@Wg^T)*(y2c@Wu^T), 256x64 tiles, 172 tasks ----
      for (int task = wid; task < 172; task += 248){
        int mt = task/43, nt = task - mt*43;
        const unsigned short* A  = y2c + (size_t)mt*256*1024;
        const unsigned short* B1 = WGT + (size_t)nt*64*1024;
        const unsigned short* B2 = WUT + (size_t)nt*64*1024;
        f32x4 acc[4], acc2[4];
        f32x4 z = {0.f,0.f,0.f,0.f};
        #pragma unroll
        for (int mi=0;mi<4;mi++){ acc[mi]=z; acc2[mi]=z; }
        for (int kt = 0; kt < 1024; kt += 32){
          GLOAD16(A + (size_t)rA*1024 + kt + uA*8, smA + w*1024);
          if (w < 4)      GLOAD16(B1 + (size_t)rB*1024 + kt + uB*8, smB  + w4*1024);
          else if (w < 8) GLOAD16(B2 + (size_t)rB*1024 + kt + uB*8, smB2 + w4*1024);
          __syncthreads();
          short8 af[4], bf, bg;
          #pragma unroll
          for (int mi=0;mi<4;mi++) af[mi] = *(const short8*)(smA + swz(wr*64 + mi*16 + (l&15), l>>4));
          bf = *(const short8*)(smB  + swz(wc*16 + (l&15), l>>4));
          bg = *(const short8*)(smB2 + swz(wc*16 + (l&15), l>>4));
          #pragma unroll
          for (int mi=0;mi<4;mi++){
            acc[mi]  = __builtin_amdgcn_mfma_f32_16x16x32_f16(as_f16x8(af[mi]), as_f16x8(bf), acc[mi], 0,0,0);
            acc2[mi] = __builtin_amdgcn_mfma_f32_16x16x32_f16(as_f16x8(af[mi]), as_f16x8(bg), acc2[mi], 0,0,0);
          }
          __syncthreads();
        }
        #pragma unroll
        for (int mi=0;mi<4;mi++)
          #pragma unroll
          for (int j=0;j<4;j++){
            int gr = wr*64 + mi*16 + (l>>4)*4 + j;
            int gc = nt*64 + wc*16 + (l&15);
            float v = acc[mi][j], u2 = acc2[mi][j];
            float sg = v*frcp(1.f + fexp2(-v*L2E));
            Sc[(size_t)(mt*256+gr)*2752 + gc] = f2h(sg*u2);
          }
      }
      sig_wait(&FLAGS[32+c], tid);

      // ---- stage G2: out = x2 + S@Wd^T, 256x64 tiles, 64 tasks ----
      for (int task = wid; task < 64; task += 248){
        int mt = task>>4, nt = task&15;
        const unsigned short* A = Sc  + (size_t)mt*256*2752;
        const unsigned short* B = WDT + (size_t)nt*64*2752;
        f32x4 acc[4];
        f32x4 z = {0.f,0.f,0.f,0.f};
        #pragma unroll
        for (int mi=0;mi<4;mi++) acc[mi]=z;
        for (int kt = 0; kt < 2752; kt += 32){
          GLOAD16(A + (size_t)rA*2752 + kt + uA*8, smA + w*1024);
          if (w < 4) GLOAD16(B + (size_t)rB*2752 + kt + uB*8, smB + w4*1024);
          __syncthreads();
          short8 af[4], bf;
          #pragma unroll
          for (int mi=0;mi<4;mi++) af[mi] = *(const short8*)(smA + swz(wr*64 + mi*16 + (l&15), l>>4));
          bf = *(const short8*)(smB + swz(wc*16 + (l&15), l>>4));
          #pragma unroll
          for (int mi=0;mi<4;mi++)
            acc[mi] = __builtin_amdgcn_mfma_f32_16x16x32_f16(as_f16x8(af[mi]), as_f16x8(bf), acc[mi], 0,0,0);
          __syncthreads();
        }
        #pragma unroll
        for (int mi=0;mi<4;mi++)
          #pragma unroll
          for (int j=0;j<4;j++){
            int gr = wr*64 + mi*16 + (l>>4)*4 + j;
            int gc = nt*64 + wc*16 + (l&15);
            int r = mt*256 + gr;                      // y2c row -> global row
            size_t m = (size_t)(r>>7)*2048 + c*128 + (r&127);
            size_t idx = m*1024 + gc;
            X2OUT[idx] = X2OUT[idx] + acc[mi][j];
          }
      }
      sig_wait(&FLAGS[48+c], tid);
    }
  }
}

// ---------------- launch ----------------------------------------------------------
extern "C" void kernel_launch(void* const* d_in, const int* in_sizes, int n_in,
                              void* d_out, int out_size, void* d_ws, size_t ws_size,
                              hipStream_t stream){
  (void)in_sizes; (void)n_in; (void)out_size;
  const float* x    = (const float*)d_in[0];
  const float* ln1w = (const float*)d_in[1];
  const float* Wg_  = (const float*)d_in[2];
  const float* Rg_  = (const float*)d_in[3];
  const float* bg_  = (const float*)d_in[4];
  const float* gnw  = (const float*)d_in[5];
  const float* ln2w = (const float*)d_in[6];
  const float* Wgf  = (const float*)d_in[7];
  const float* Wuf  = (const float*)d_in[8];
  const float* Wdf  = (const float*)d_in[9];
  float* out = (float*)d_out;
  char* ws = (char*)d_ws;

  // workspace layout (total 187,858,944 B):
  //   [0..20.1M)   persistent weights; bias region doubles as FLAGS post-gemm0
  //   [20.1M..53.6M)  xn' (rms1 out, [t*8+b] rows) -> hs (scan out)
  //   [53.6M..187.9M) gx; per-chunk scratch (y2c+Sc) reuses gx chunk c's 8MB region
  //   x2 lives in d_out (fully rewritten each launch)
  if (ws_size < 187858944ull) return;
  unsigned short* wbt = (unsigned short*)(ws + 0);
  float*          bias= (float*)        (ws + 2097152);
  int*            flags=(int*)          (ws + 2097152);   // aliases bias (dead post-gemm0)
  signed char*    rq  = (signed char*)  (ws + 2113536);
  float*          sc2 = (float*)        (ws + 3162112);
  unsigned short* wgt = (unsigned short*)(ws + 3178496);
  unsigned short* wut = (unsigned short*)(ws + 8814592);
  unsigned short* wdt = (unsigned short*)(ws + 14450688);
  unsigned short* xn  = (unsigned short*)(ws + 20086784);
  unsigned short* hs  = (unsigned short*)(ws + 20086784);  // aliases xn
  unsigned short* gx  = (unsigned short*)(ws + 53641216);

  prep_wbt<<<4096,256,0,stream>>>(Wg_, bg_, wbt, bias);
  prep_rq <<<4096,256,0,stream>>>(Rg_, rq, sc2);
  transpose_cast<<<dim3(86,32),256,0,stream>>>(Wgf, wgt, 1024, 2752);
  transpose_cast<<<dim3(86,32),256,0,stream>>>(Wuf, wut, 1024, 2752);
  transpose_cast<<<dim3(32,86),256,0,stream>>>(Wdf, wdt, 2752, 1024);

  rmsnorm_k<<<16384,256,0,stream>>>(x, ln1w, xn);
  gemm0_k<<<dim3(8,128,4),256,0,stream>>>(xn, wbt, gx, bias);
  hipMemsetAsync(flags, 0, 256, stream);
  mega_k<<<256,1024,0,stream>>>(gx, rq, sc2, hs, flags, x, gnw, ln2w,
                                wgt, wut, wdt, (char*)gx, out);
}

// Round 17
// 1946.293 us; speedup vs baseline: 3.2322x; 1.3041x over previous
//
#include <hip/hip_runtime.h>
#include <hip/hip_bf16.h>

#define DEV __device__ __forceinline__

typedef __attribute__((ext_vector_type(4))) float f32x4;
typedef __attribute__((ext_vector_type(8))) short short8;
typedef __attribute__((ext_vector_type(8))) _Float16 f16x8;
typedef __attribute__((ext_vector_type(4))) int i32x4;
typedef __attribute__((ext_vector_type(4))) unsigned short u16x4;
typedef __attribute__((ext_vector_type(8))) unsigned short u16x8;

typedef __attribute__((address_space(3))) void lds_void;
typedef const __attribute__((address_space(1))) void g_void;
#define GLOAD16(g, l) __builtin_amdgcn_global_load_lds((g_void*)(g), (lds_void*)(l), 16, 0, 0)

DEV unsigned short f2h(float f){ union{_Float16 h; unsigned short u;} c; c.h = (_Float16)f; return c.u; }
DEV float h2f(unsigned short u){ union{unsigned short u; _Float16 h;} c; c.u = u; return (float)c.h; }
DEV f16x8 as_f16x8(short8 s){ union{short8 s; f16x8 h;} c; c.s = s; return c.h; }
DEV float fexp2(float x){
#if __has_builtin(__builtin_amdgcn_exp2f)
  return __builtin_amdgcn_exp2f(x);
#else
  return exp2f(x);
#endif
}
DEV float frcp(float x){
#if __has_builtin(__builtin_amdgcn_rcpf)
  return __builtin_amdgcn_rcpf(x);
#else
  return 1.f/x;
#endif
}
DEV float wsum(float v){
  #pragma unroll
  for(int o=32;o;o>>=1) v += __shfl_xor(v,o,64);
  return v;
}
DEV float wmax_(float v){
  #pragma unroll
  for(int o=32;o;o>>=1) v = fmaxf(v,__shfl_xor(v,o,64));
  return v;
}
// XOR swizzle for [rows][32 fp16] LDS tiles, row stride 64B, 16B units.
DEV int swz(int row, int unit){ return row*64 + ((unit ^ ((row>>1)&3))<<4); }

// ---------------- prep: W_gates fp32 -> fp16 bt-layout [n][C'=(k<<2)|g][h] -------
__global__ __launch_bounds__(256) void prep_wbt(const float* __restrict__ W,
    const float* __restrict__ BG, unsigned short* __restrict__ WBT, float* __restrict__ BIAS){
  int bid = blockIdx.x;                 // (g,n,k) row-major, 4096 blocks
  int g = bid>>10, n = (bid>>8)&3, k = bid&255;
  int C = (k<<2) | g;                   // gx-granule-aligned column code
  int h = threadIdx.x;
  WBT[((size_t)n*1024 + C)*256 + h] = f2h(W[(size_t)bid*256 + h]);
  if (h==0) BIAS[n*1024 + C] = BG[(g*4+n)*256 + k];
}

// ---------------- prep: R_gates fp32 -> int8 fragment layout + per-col scales ----
__global__ __launch_bounds__(256) void prep_rq(const float* __restrict__ R,
    signed char* __restrict__ RQ, float* __restrict__ SC){
  int bid = blockIdx.x;                 // (g,n,k)
  int g = bid>>10, n = (bid>>8)&3, k = bid&255;
  int h = threadIdx.x;
  float v = R[(size_t)bid*256 + h];
  float a = fabsf(v);
  float m = wmax_(a);
  __shared__ float red[4];
  int wv = threadIdx.x>>6, l = threadIdx.x&63;
  if (!l) red[wv] = m;
  __syncthreads();
  m = fmaxf(fmaxf(red[0],red[1]), fmaxf(red[2],red[3]));
  float s = fmaxf(m, 1e-20f) * (1.f/127.f);
  int q = (int)rintf(v/s);
  q = q > 127 ? 127 : (q < -127 ? -127 : q);
  int w  = k>>5, kblk = (k>>4)&1, f = (kblk<<2)|g, kf = h>>6;
  int ln = (k&15) | (((h>>4)&3)<<4);
  int j  = h&15;
  RQ[ (((size_t)(n*8+w)*32 + (f*4+kf))*64 + ln)*16 + j ] = (signed char)q;
  if (h==0) SC[n*1024 + g*256 + k] = s * (1.f/127.f);
}

// ---------------- prep: transpose fp32 [K][N] -> fp16 [N][K] ----------------------
__global__ __launch_bounds__(256) void transpose_cast(const float* __restrict__ IN,
    unsigned short* __restrict__ OUT, int K, int N){
  __shared__ float tile[32][33];
  int n0 = blockIdx.x*32, k0 = blockIdx.y*32;
  int c = threadIdx.x&31, r4 = threadIdx.x>>5;
  #pragma unroll
  for (int rr = r4; rr < 32; rr += 8) tile[rr][c] = IN[(size_t)(k0+rr)*N + n0 + c];
  __syncthreads();
  #pragma unroll
  for (int rr = r4; rr < 32; rr += 8) OUT[(size_t)(n0+rr)*K + k0 + c] = f2h(tile[c][rr]);
}

// ---------------- rmsnorm fp32 -> fp16, output row permuted to [t][b] -------------
__global__ __launch_bounds__(256) void rmsnorm_k(const float* __restrict__ X,
    const float* __restrict__ W, unsigned short* __restrict__ O){
  size_t row = blockIdx.x;
  const f32x4* xp = (const f32x4*)(X + row*1024);
  f32x4 v = xp[threadIdx.x];
  float s = v[0]*v[0]+v[1]*v[1]+v[2]*v[2]+v[3]*v[3];
  s = wsum(s);
  __shared__ float red[4];
  int wv = threadIdx.x>>6, l = threadIdx.x&63;
  if (!l) red[wv] = s;
  __syncthreads();
  float tot = red[0]+red[1]+red[2]+red[3];
  float rs = rsqrtf(tot*(1.f/1024.f) + 1e-6f);
  int c = threadIdx.x*4;
  u16x4 o;
  #pragma unroll
  for (int j=0;j<4;j++) o[j] = f2h(v[j]*rs*W[c+j]);
  size_t orow = (row & 2047)*8 + (row >> 11);   // xn' row = t*8 + b
  *(u16x4*)(O + orow*1024 + c) = o;
}

// ---------------- gate GEMM, 128x128 tile, LDS-staged coalesced gx write ----------
__global__ __launch_bounds__(256,2) void gemm0_k(
    const unsigned short* __restrict__ A, const unsigned short* __restrict__ B1,
    unsigned short* __restrict__ OB, const float* __restrict__ BIAS){
  __shared__ __align__(16) char smem[32768];
  char* smA = smem;
  char* smB = smem + 8192;
  int tid = threadIdx.x, w = tid>>6, l = tid&63;
  int n0 = blockIdx.x*128, m0 = blockIdx.y*128, head = blockIdx.z;
  A += (size_t)head*256; B1 += (size_t)head*1024*256;
  f32x4 acc[4][4];
  f32x4 z = {0.f,0.f,0.f,0.f};
  #pragma unroll
  for (int mi=0;mi<4;mi++)
    #pragma unroll
    for (int ni=0;ni<4;ni++) acc[mi][ni]=z;
  int wr = w>>1, wc = w&1;
  for (int kt = 0; kt < 256; kt += 32){
    #pragma unroll
    for (int c2=0;c2<2;c2++){
      int p = c2*256 + tid;
      int rr = p>>2, u = (p&3) ^ ((rr>>1)&3);
      int ldsb = (c2*256 + w*64)*16;
      GLOAD16(A  + (size_t)(m0+rr)*1024 + kt + u*8, smA + ldsb);
      GLOAD16(B1 + (size_t)(n0+rr)*256  + kt + u*8, smB + ldsb);
    }
    __syncthreads();
    short8 af[4], bf[4];
    #pragma unroll
    for (int mi=0;mi<4;mi++) af[mi] = *(const short8*)(smA + swz(wr*64 + mi*16 + (l&15), l>>4));
    #pragma unroll
    for (int ni=0;ni<4;ni++) bf[ni] = *(const short8*)(smB + swz(wc*64 + ni*16 + (l&15), l>>4));
    #pragma unroll
    for (int mi=0;mi<4;mi++)
      #pragma unroll
      for (int ni=0;ni<4;ni++)
        acc[mi][ni] = __builtin_amdgcn_mfma_f32_16x16x32_f16(as_f16x8(af[mi]), as_f16x8(bf[ni]), acc[mi][ni], 0,0,0);
    __syncthreads();
  }
  // stage tile to LDS in gx granule order, then coalesced 2KB-row streaming store
  unsigned short* gt = (unsigned short*)smem;
  #pragma unroll
  for (int mi=0;mi<4;mi++)
    #pragma unroll
    for (int ni=0;ni<4;ni++)
      #pragma unroll
      for (int j=0;j<4;j++){
        int rr = wr*64 + mi*16 + (l>>4)*4 + j;
        int cc = wc*64 + ni*16 + (l&15);
        int Cp = n0 + cc;
        int g = Cp & 3, b = rr & 7;
        float fac = (g==2) ? 2.8853900817779268f : 1.4426950408889634f;
        gt[ (rr>>3)*1024 + (cc>>2)*32 + (b>>1)*8 + (b&1)*4 + g ]
          = f2h((acc[mi][ni][j] + BIAS[head*1024 + Cp]) * fac);
      }
  __syncthreads();
  int t0 = blockIdx.y*16, k0 = blockIdx.x*32;
  int t_loc = tid>>4, seg = tid&15;
  const u16x8* src = (const u16x8*)(gt + t_loc*1024 + seg*64);
  u16x8* dst = (u16x8*)(OB + ((((size_t)(t0+t_loc)*4 + head)*256 + k0)*32) + seg*64);
  #pragma unroll
  for (int i=0;i<8;i++) dst[i] = src[i];
}

// ================== MEGA kernel: scan (WG 0-7) + downstream workers (WG 8-255) ====
// 8 chunks of 256 steps (round-16 lesson: per-chunk overhead ~62us, minimize count).
// Worker GEMM K-loops are double-buffered (stage next tile BEFORE compute, one
// __syncthreads per phase) -> load latency hides under MFMA. Third per-chunk
// barrier dropped (chunk regions + X2OUT rows disjoint; N->G1 barrier of c+1
// provides all needed ordering).
#define SCAN_STEP(HR, HW, GXV, TT) do{                                          \
    i32x4 af[4];                                                                \
    _Pragma("unroll")                                                           \
    for (int kf=0;kf<4;kf++) af[kf] = *(const i32x4*)(&HR[ra + kf*64]);         \
    i32x4 acc[4];                                                               \
    _Pragma("unroll")                                                           \
    for (int g=0; g<4; g++){                                                    \
      i32x4 a = {0,0,0,0};                                                      \
      _Pragma("unroll")                                                         \
      for (int kf=0; kf<4; kf++)                                                \
        a = __builtin_amdgcn_mfma_i32_16x16x64_i8(af[kf], wf[g][kf], a, 0,0,0); \
      acc[g] = a;                                                               \
    }                                                                           \
    float ip2 = fmaf(sch[0],(float)acc[0][0], fmaf(scl[0],(float)acc[0][1], h2f(GXV[0]))); \
    float fpv = fmaf(sch[1],(float)acc[1][0], fmaf(scl[1],(float)acc[1][1], h2f(GXV[1]))) + ms; \
    float zp2 = fmaf(sch[2],(float)acc[2][0], fmaf(scl[2],(float)acc[2][1], h2f(GXV[2]))); \
    float op2 = fmaf(sch[3],(float)acc[3][0], fmaf(scl[3],(float)acc[3][1], h2f(GXV[3]))); \
    float mn = fmaxf(fpv, ip2);                                                 \
    float ig = fexp2(ip2 - mn);                                                 \
    float fg = fexp2(fpv - mn);                                                 \
    float e2 = fexp2(zp2);                                                      \
    float tz = fmaf(-2.f, frcp(e2 + 1.f), 1.f);                                 \
    float eo = fexp2(-op2);                                                     \
    float c  = fmaf(ig, tz, fg*cs);                                             \
    float nn = fmaf(fg, ns_, ig);                                               \
    float h  = c * frcp((1.f + eo)*nn);                                         \
    cs=c; ns_=nn; ms=mn;                                                        \
    float h127 = h*127.f;                                                       \
    float hiq = rintf(h127);                                                    \
    float loq = rintf((h127 - hiq)*127.f);                                      \
    HW[r_hi] = (signed char)(int)hiq;                                           \
    HW[r_lo] = (signed char)(int)loq;                                           \
    HS[(size_t)(TT)*8192 + hoff] = f2h(h);                                      \
  }while(0)

DEV void slow_spin(int* f, int n){
  while (__hip_atomic_load(f, __ATOMIC_RELAXED, __HIP_MEMORY_SCOPE_AGENT) < n)
    __builtin_amdgcn_s_sleep(127);
  (void)__hip_atomic_load(f, __ATOMIC_ACQUIRE, __HIP_MEMORY_SCOPE_AGENT);
}

DEV void sig_wait(int* f, int tid){
  asm volatile("s_waitcnt vmcnt(0) lgkmcnt(0)" ::: "memory");
  __syncthreads();
  if (tid==0){
    __hip_atomic_fetch_add(f, 1, __ATOMIC_RELEASE, __HIP_MEMORY_SCOPE_AGENT);
    slow_spin(f, 248);
  }
  __syncthreads();
}

__global__ __launch_bounds__(1024,4) void mega_k(
    const unsigned short* GX, const signed char* RQ, const float* SC,
    unsigned short* HS, int* FLAGS,
    const float* X, const float* GNW, const float* LN2W,
    const unsigned short* WGT, const unsigned short* WUT, const unsigned short* WDT,
    char* CHUNK0, float* X2OUT){
  __shared__ __align__(16) char smem[86016];   // 1 WG/CU
  int tid = threadIdx.x;
  const float L2E = 1.44269504f;

  if (blockIdx.x < 8){
    // ---------------- scan path (unchanged core) ----------------
    int bid = blockIdx.x;
    int n = bid >> 1, bg = bid & 1;
    int w = tid>>6, l = tid&63;
    signed char* hlA = (signed char*)smem;
    signed char* hlB = (signed char*)(smem + 4352);
    for (int i = tid; i < 8704; i += 1024) smem[i] = 0;

    int l15 = l & 15, q = l >> 4;
    i32x4 wf[4][4];
    {
      const i32x4* rp = (const i32x4*)RQ + (size_t)(n*8 + (w>>1))*32*64;
      #pragma unroll
      for (int g=0; g<4; g++){
        int f = ((w&1)<<2) | g;
        #pragma unroll
        for (int kf=0; kf<4; kf++)
          wf[g][kf] = rp[(f*4+kf)*64 + l];
      }
    }
    float sch[4], scl[4];
    {
      const float facs[4] = {1.4426950408889634f, 1.4426950408889634f,
                             2.8853900817779268f, 1.4426950408889634f};
      #pragma unroll
      for (int g=0; g<4; g++){
        float s = SC[n*1024 + g*256 + w*16 + l15] * facs[g];
        sch[g] = s; scl[g] = s*(1.f/127.f);
      }
    }
    float cs = 0.f, ns_ = 0.f, ms = 0.f;
    int goff = (n*256 + w*16 + l15)*32 + (bg*2 + (q>>1))*8 + (q&1)*4;
    int hoff = (n*8 + bg*4 + q)*256 + w*16 + l15;
    int ra   = l15*272 + q*16;
    int r_hi = (4*q + 0)*272 + w*16 + l15;
    int r_lo = r_hi + 272;

    u16x4 gxr = *(const u16x4*)(GX + goff);
    __syncthreads();

    for (int t = 0; t < 2048; t += 2){
      u16x4 gx1 = *(const u16x4*)(GX + (size_t)(t+1)*32768 + goff);
      SCAN_STEP(hlA, hlB, gxr, t);
      asm volatile("s_waitcnt lgkmcnt(0)" ::: "memory");
      __builtin_amdgcn_s_barrier();
      __builtin_amdgcn_sched_barrier(0);
      int tt2 = (t+2 < 2048) ? (t+2) : 2047;
      gxr = *(const u16x4*)(GX + (size_t)tt2*32768 + goff);
      SCAN_STEP(hlB, hlA, gx1, t+1);
      asm volatile("s_waitcnt lgkmcnt(0)" ::: "memory");
      __builtin_amdgcn_s_barrier();
      __builtin_amdgcn_sched_barrier(0);
      if (((t+2) & 255) == 0){
        asm volatile("s_waitcnt vmcnt(0)" ::: "memory");
        __builtin_amdgcn_s_barrier();
        if (tid == 0)
          __hip_atomic_fetch_add(&FLAGS[(t+1)>>8], 1, __ATOMIC_RELEASE, __HIP_MEMORY_SCOPE_AGENT);
      }
    }
  } else {
    // ---------------- worker path ----------------
    int wid = blockIdx.x - 8;               // 0..247
    int w = tid>>6, l = tid&63;
    int wr = w>>2, wc = w&3;                 // 4x4 wave grid, wave tile 64x16
    char* smA0 = smem;                       // 16KB
    char* smB0 = smem + 16384;               // 4KB
    char* smC0 = smem + 20480;               // 4KB
    char* smA1 = smem + 24576;               // 16KB
    char* smB1b= smem + 40960;               // 4KB
    char* smC1 = smem + 45056;               // 4KB
    float* red = (float*)(smem + 49152);

    int pA = w*64 + l, rA = pA>>2, uA = (pA&3)^((rA>>1)&3);
    int w4 = w & 3;
    int pB = w4*64 + l, rB = pB>>2, uB = (pB&3)^((rB>>1)&3);

    for (int c = 0; c < 8; ++c){
      char* cb = CHUNK0 + (size_t)c*16777216;
      unsigned short* y2c = (unsigned short*)cb;
      unsigned short* Sc  = (unsigned short*)(cb + 4194304);

      if (tid==0) slow_spin(&FLAGS[c], 8);
      __syncthreads();

      // ---- stage N: x2 = x + LN(hs)*gnw ; y2c = rmsnorm(x2)*ln2w ----
      {
        int hn = tid>>8, hk = tid&255;
        for (int r = wid; r < 2048; r += 248){
          int b = r>>8, tl = r&255, t = c*256 + tl;
          float v = h2f(HS[(((size_t)t*4+hn)*8+b)*256 + hk]);
          float s1 = wsum(v), s2 = wsum(v*v);
          if (!(tid&63)){ red[tid>>6] = s1; red[16+(tid>>6)] = s2; }
          __syncthreads();
          float sum = 0.f, sq = 0.f;
          #pragma unroll
          for (int i=0;i<4;i++){ sum += red[hn*4+i]; sq += red[16+hn*4+i]; }
          float mu = sum*(1.f/256.f);
          float var = sq*(1.f/256.f) - mu*mu;
          float rs = rsqrtf(var + 1e-5f);
          size_t xi = (size_t)(b*2048+t)*1024 + tid;
          float x2v = X[xi] + (v-mu)*rs*GNW[tid];
          X2OUT[xi] = x2v;
          float qq = wsum(x2v*x2v);
          if (!(tid&63)) red[32+(tid>>6)] = qq;
          __syncthreads();
          float tot = 0.f;
          #pragma unroll
          for (int i=0;i<16;i++) tot += red[32+i];
          float rs2 = rsqrtf(tot*(1.f/1024.f) + 1e-6f);
          y2c[(size_t)r*1024 + tid] = f2h(x2v*rs2*LN2W[tid]);
          __syncthreads();
        }
      }
      sig_wait(&FLAGS[8+c], tid);

      // ---- stage G1: S = silu(y2c@Wg^T)*(y2c@Wu^T), 256x64 tiles, 344 tasks ----
      // double-buffered: stage next K-tile BEFORE computing current one.
      for (int task = wid; task < 344; task += 248){
        int mt = task/43, nt = task - mt*43;
        const unsigned short* A  = y2c + (size_t)mt*256*1024;
        const unsigned short* B1 = WGT + (size_t)nt*64*1024;
        const unsigned short* B2 = WUT + (size_t)nt*64*1024;
        f32x4 acc[4], acc2[4];
        f32x4 z = {0.f,0.f,0.f,0.f};
        #pragma unroll
        for (int mi=0;mi<4;mi++){ acc[mi]=z; acc2[mi]=z; }
        auto g1stage = [&](char* sa, char* sb, char* sc, int KT){
          GLOAD16(A + (size_t)rA*1024 + KT + uA*8, sa + w*1024);
          if (w < 4)      GLOAD16(B1 + (size_t)rB*1024 + KT + uB*8, sb + w4*1024);
          else if (w < 8) GLOAD16(B2 + (size_t)rB*1024 + KT + uB*8, sc + w4*1024);
        };
        auto g1comp = [&](char* sa, char* sb, char* sc){
          short8 af[4], bf, bg;
          #pragma unroll
          for (int mi=0;mi<4;mi++) af[mi] = *(const short8*)(sa + swz(wr*64 + mi*16 + (l&15), l>>4));
          bf = *(const short8*)(sb + swz(wc*16 + (l&15), l>>4));
          bg = *(const short8*)(sc + swz(wc*16 + (l&15), l>>4));
          #pragma unroll
          for (int mi=0;mi<4;mi++){
            acc[mi]  = __builtin_amdgcn_mfma_f32_16x16x32_f16(as_f16x8(af[mi]), as_f16x8(bf), acc[mi], 0,0,0);
            acc2[mi] = __builtin_amdgcn_mfma_f32_16x16x32_f16(as_f16x8(af[mi]), as_f16x8(bg), acc2[mi], 0,0,0);
          }
        };
        g1stage(smA0, smB0, smC0, 0);
        __syncthreads();
        for (int kt = 0; kt < 1024; kt += 64){
          g1stage(smA1, smB1b, smC1, kt+32);
          g1comp(smA0, smB0, smC0);
          __syncthreads();
          if (kt+64 < 1024) g1stage(smA0, smB0, smC0, kt+64);
          g1comp(smA1, smB1b, smC1);
          __syncthreads();
        }
        #pragma unroll
        for (int mi=0;mi<4;mi++)
          #pragma unroll
          for (int j=0;j<4;j++){
            int gr = wr*64 + mi*16 + (l>>4)*4 + j;
            int gc = nt*64 + wc*16 + (l&15);
            float v = acc[mi][j], u2 = acc2[mi][j];
            float sg = v*frcp(1.f + fexp2(-v*L2E));
            Sc[(size_t)(mt*256+gr)*2752 + gc] = f2h(sg*u2);
          }
      }
      sig_wait(&FLAGS[16+c], tid);

      // ---- stage G2: out = x2 + S@Wd^T, 256x64 tiles, 128 tasks ----
      for (int task = wid; task < 128; task += 248){
        int mt = task>>4, nt = task&15;
        const unsigned short* A = Sc  + (size_t)mt*256*2752;
        const unsigned short* B = WDT + (size_t)nt*64*2752;
        f32x4 acc[4];
        f32x4 z = {0.f,0.f,0.f,0.f};
        #pragma unroll
        for (int mi=0;mi<4;mi++) acc[mi]=z;
        auto g2stage = [&](char* sa, char* sb, int KT){
          GLOAD16(A + (size_t)rA*2752 + KT + uA*8, sa + w*1024);
          if (w < 4) GLOAD16(B + (size_t)rB*2752 + KT + uB*8, sb + w4*1024);
        };
        auto g2comp = [&](char* sa, char* sb){
          short8 af[4], bf;
          #pragma unroll
          for (int mi=0;mi<4;mi++) af[mi] = *(const short8*)(sa + swz(wr*64 + mi*16 + (l&15), l>>4));
          bf = *(const short8*)(sb + swz(wc*16 + (l&15), l>>4));
          #pragma unroll
          for (int mi=0;mi<4;mi++)
            acc[mi] = __builtin_amdgcn_mfma_f32_16x16x32_f16(as_f16x8(af[mi]), as_f16x8(bf), acc[mi], 0,0,0);
        };
        g2stage(smA0, smB0, 0);
        __syncthreads();
        for (int kt = 0; kt < 2752; kt += 64){
          g2stage(smA1, smB1b, kt+32);
          g2comp(smA0, smB0);
          __syncthreads();
          if (kt+64 < 2752) g2stage(smA0, smB0, kt+64);
          g2comp(smA1, smB1b);
          __syncthreads();
        }
        #pragma unroll
        for (int mi=0;mi<4;mi++)
          #pragma unroll
          for (int j=0;j<4;j++){
            int gr = wr*64 + mi*16 + (l>>4)*4 + j;
            int gc = nt*64 + wc*16 + (l&15);
            size_t idx = (size_t)(mt*2048 + c*256 + gr)*1024 + gc;
            X2OUT[idx] = X2OUT[idx] + acc[mi][j];
          }
      }
      // no barrier here: chunk regions + X2OUT rows disjoint; next chunk's
      // N->G1 sig_wait provides the ordering G1(c+1) needs.
    }
  }
}

// ---------------- launch ----------------------------------------------------------
extern "C" void kernel_launch(void* const* d_in, const int* in_sizes, int n_in,
                              void* d_out, int out_size, void* d_ws, size_t ws_size,
                              hipStream_t stream){
  (void)in_sizes; (void)n_in; (void)out_size;
  const float* x    = (const float*)d_in[0];
  const float* ln1w = (const float*)d_in[1];
  const float* Wg_  = (const float*)d_in[2];
  const float* Rg_  = (const float*)d_in[3];
  const float* bg_  = (const float*)d_in[4];
  const float* gnw  = (const float*)d_in[5];
  const float* ln2w = (const float*)d_in[6];
  const float* Wgf  = (const float*)d_in[7];
  const float* Wuf  = (const float*)d_in[8];
  const float* Wdf  = (const float*)d_in[9];
  float* out = (float*)d_out;
  char* ws = (char*)d_ws;

  // workspace layout (total 187,858,944 B):
  //   [0..20.1M)   persistent weights; bias region doubles as FLAGS post-gemm0
  //   [20.1M..53.6M)  xn' (rms1 out, [t*8+b] rows) -> hs (scan out)
  //   [53.6M..187.9M) gx; per-chunk scratch (y2c+Sc) reuses gx chunk c's 16MB region
  //   x2 lives in d_out (fully rewritten each launch)
  if (ws_size < 187858944ull) return;
  unsigned short* wbt = (unsigned short*)(ws + 0);
  float*          bias= (float*)        (ws + 2097152);
  int*            flags=(int*)          (ws + 2097152);   // aliases bias (dead post-gemm0)
  signed char*    rq  = (signed char*)  (ws + 2113536);
  float*          sc2 = (float*)        (ws + 3162112);
  unsigned short* wgt = (unsigned short*)(ws + 3178496);
  unsigned short* wut = (unsigned short*)(ws + 8814592);
  unsigned short* wdt = (unsigned short*)(ws + 14450688);
  unsigned short* xn  = (unsigned short*)(ws + 20086784);
  unsigned short* hs  = (unsigned short*)(ws + 20086784);  // aliases xn
  unsigned short* gx  = (unsigned short*)(ws + 53641216);

  prep_wbt<<<4096,256,0,stream>>>(Wg_, bg_, wbt, bias);
  prep_rq <<<4096,256,0,stream>>>(Rg_, rq, sc2);
  transpose_cast<<<dim3(86,32),256,0,stream>>>(Wgf, wgt, 1024, 2752);
  transpose_cast<<<dim3(86,32),256,0,stream>>>(Wuf, wut, 1024, 2752);
  transpose_cast<<<dim3(32,86),256,0,stream>>>(Wdf, wdt, 2752, 1024);

  rmsnorm_k<<<16384,256,0,stream>>>(x, ln1w, xn);
  gemm0_k<<<dim3(8,128,4),256,0,stream>>>(xn, wbt, gx, bias);
  hipMemsetAsync(flags, 0, 128, stream);
  mega_k<<<256,1024,0,stream>>>(gx, rq, sc2, hs, flags, x, gnw, ln2w,
                                wgt, wut, wdt, (char*)gx, out);
}